// Round 1
// baseline (628.701 us; speedup 1.0000x reference)
//
#include <hip/hip_runtime.h>

#define C_ 32
#define D_ 48
#define H_ 64
#define W_ 128
#define HW_ 8192

using short8 = __attribute__((ext_vector_type(8))) short;
using f32x4  = __attribute__((ext_vector_type(4))) float;

__device__ __forceinline__ unsigned short f2bf(float f) {
    unsigned u = __builtin_bit_cast(unsigned, f);
    unsigned r = (u + 0x7fffu + ((u >> 16) & 1u)) >> 16;
    return (unsigned short)r;
}

// x[c][d][h][w] -> xt[c][h][w][d]
__global__ __launch_bounds__(256) void k_transpose(const float* __restrict__ x,
                                                   float* __restrict__ xt) {
    __shared__ float tile[48 * 129];
    const int t = threadIdx.x;
    const int c = blockIdx.x >> 6, h = blockIdx.x & 63;
    const float* xb = x + c * (D_ * HW_) + h * W_;
#pragma unroll
    for (int i = 0; i < 24; ++i) {
        int idx = i * 256 + t;
        int d = idx >> 7, w = idx & 127;
        tile[d * 129 + w] = xb[d * HW_ + w];
    }
    __syncthreads();
    float* xo = xt + ((c * H_ + h) * W_) * D_;
#pragma unroll
    for (int i = 0; i < 32; ++i) {
        int idx = i * 256 + t;
        int w = idx >> 6, dl = idx & 63;
        if (dl < 48) xo[w * D_ + dl] = tile[dl * 129 + w];
    }
}

// One wave per line; lane = d. DIR: 0=W fwd, 1=W rev, 2=H fwd, 3=H rev.
// DIR 0 stores A; DIR>0 stores max(A, agg).
template <int DIR>
__global__ __launch_bounds__(256) void k_scan(const float* __restrict__ xt,
                                              const float* __restrict__ g,
                                              float* __restrict__ agg) {
    constexpr bool AX_W = (DIR < 2);
    constexpr bool REV = (DIR & 1);
    constexpr bool CMB = (DIR > 0);
    constexpr int T = AX_W ? W_ : H_;
    const int lane = threadIdx.x & 63;
    const int gw = blockIdx.x * 4 + (threadIdx.x >> 6);
    const bool act = lane < 48;
    int base, ss, gbase, gstep;
    if (AX_W) {
        int c = gw >> 6, h = gw & 63;
        base = (c * H_ + h) * W_ * D_;
        ss = D_;
        gbase = ((DIR * C_ + c) * 5 * H_ + h) * W_;
        gstep = 1;
    } else {
        int c = gw >> 7, w = gw & 127;
        base = (c * HW_ + w) * D_;
        ss = W_ * D_;
        gbase = ((DIR * C_ + c) * 5 * H_) * W_ + w;
        gstep = W_;
    }
    // p = 0 (boundary: A = C)
    int q = REV ? (T - 1) : 0;
    float xv = act ? xt[base + q * ss + lane] : 0.f;
    float prev = xv;
    {
        float o = prev;
        if (CMB) {
            float av = act ? agg[base + q * ss + lane] : 0.f;
            o = fmaxf(o, av);
        }
        if (act) agg[base + q * ss + lane] = o;
    }
    // prefetch p = 1
    q = REV ? (T - 2) : 1;
    float nx = act ? xt[base + q * ss + lane] : 0.f;
    float nk0 = g[gbase + 0 * HW_ + q * gstep];
    float nk1 = g[gbase + 1 * HW_ + q * gstep];
    float nk2 = g[gbase + 2 * HW_ + q * gstep];
    float nk3 = g[gbase + 3 * HW_ + q * gstep];
    float nk4 = g[gbase + 4 * HW_ + q * gstep];
    float na = CMB ? (act ? agg[base + q * ss + lane] : 0.f) : 0.f;

    for (int p = 1; p < T; ++p) {
        float x0 = nx, k0 = nk0, k1 = nk1, k2 = nk2, k3 = nk3, k4 = nk4, av = na;
        if (p + 1 < T) {
            int qn = REV ? (T - 2 - p) : (p + 1);
            nx = act ? xt[base + qn * ss + lane] : 0.f;
            nk0 = g[gbase + 0 * HW_ + qn * gstep];
            nk1 = g[gbase + 1 * HW_ + qn * gstep];
            nk2 = g[gbase + 2 * HW_ + qn * gstep];
            nk3 = g[gbase + 3 * HW_ + qn * gstep];
            nk4 = g[gbase + 4 * HW_ + qn * gstep];
            na = CMB ? (act ? agg[base + qn * ss + lane] : 0.f) : 0.f;
        }
        float s = fabsf(k0) + fabsf(k1) + fabsf(k2) + fabsf(k3) + fabsf(k4);
        float rn = 1.f / fmaxf(s, 1e-12f);
        k0 *= rn; k1 *= rn; k2 *= rn; k3 *= rn; k4 *= rn;
        float pz = act ? prev : 0.f;
        float dm = __shfl_up(pz, 1);
        if (lane == 0) dm = 0.f;
        float dp = __shfl_down(pz, 1);  // lane47 pulls lane48's 0
        float mx = act ? prev : -INFINITY;
        mx = fmaxf(mx, __shfl_xor(mx, 32));
        mx = fmaxf(mx, __shfl_xor(mx, 16));
        mx = fmaxf(mx, __shfl_xor(mx, 8));
        mx = fmaxf(mx, __shfl_xor(mx, 4));
        mx = fmaxf(mx, __shfl_xor(mx, 2));
        mx = fmaxf(mx, __shfl_xor(mx, 1));
        float a = k0 * x0 + k1 * prev + k2 * dm + k3 * dp + k4 * mx;
        prev = a;
        int qq = REV ? (T - 1 - p) : p;
        float ov = CMB ? fmaxf(a, av) : a;
        if (act) agg[base + qq * ss + lane] = ov;
    }
}

// agg[c][h][w][d] -> y2[h][w][dpad(50)][c] bf16, with BN1+ReLU, d-pad zeros.
__global__ __launch_bounds__(256) void k_prep(const float* __restrict__ agg,
                                              const float* __restrict__ bn1s,
                                              const float* __restrict__ bn1b,
                                              unsigned short* __restrict__ y2) {
    __shared__ float L[48 * 33];
    __shared__ float s_inv[32], s_b[32];
    const int t = threadIdx.x;
    if (t < 32) {
        s_inv[t] = bn1s[t] * rsqrtf(1.f + 1e-5f);
        s_b[t] = bn1b[t];
    }
    __syncthreads();
    const int h = blockIdx.x >> 4;
    const int w0 = (blockIdx.x & 15) * 8;
    for (int wi = 0; wi < 8; ++wi) {
        int w = w0 + wi;
#pragma unroll
        for (int i = 0; i < 6; ++i) {
            int idx = i * 256 + t;  // 0..1535
            int c = idx / 48, d = idx - c * 48;
            float v = agg[((c * H_ + h) * W_ + w) * D_ + d];
            L[d * 33 + c] = fmaxf(v * s_inv[c] + s_b[c], 0.f);
        }
        __syncthreads();
#pragma unroll
        for (int i = 0; i < 7; ++i) {
            int idx = i * 256 + t;
            if (idx < 1600) {
                int c = idx & 31, dp = idx >> 5;
                float v = (dp == 0 || dp == 49) ? 0.f : L[(dp - 1) * 33 + c];
                y2[(h * W_ + w) * 1600 + dp * 32 + c] = f2bf(v);
            }
        }
        __syncthreads();
    }
}

// w_refine[co][ci][tap] -> wt[tap][co][ci] bf16
__global__ __launch_bounds__(256) void k_wprep(const float* __restrict__ wr,
                                               unsigned short* __restrict__ wt) {
    int idx = blockIdx.x * 256 + threadIdx.x;  // 27648 total
    int ci = idx & 31, co = (idx >> 5) & 31, tap = idx >> 10;
    wt[(tap * 32 + co) * 32 + ci] = f2bf(wr[(co * 32 + ci) * 27 + tap]);
}

// Implicit-GEMM conv 3x3x3 via MFMA 16x16x32 bf16. M=c_out(32), N=d(48), K=c_in(32).
// Block tile: 2h x 2w positions, full d, full c_out. + BN2 + residual + ReLU.
__global__ __launch_bounds__(256) void k_conv(const unsigned short* __restrict__ y2,
                                              const unsigned short* __restrict__ wt,
                                              const float* __restrict__ x,
                                              const float* __restrict__ bn2s,
                                              const float* __restrict__ bn2b,
                                              float* __restrict__ out) {
    __shared__ __align__(16) char lds[64000];
    unsigned short* ys = (unsigned short*)lds;  // [row16][dpad50][cpad40]
    const int t = threadIdx.x;
    const int h0 = (blockIdx.x >> 6) * 2;
    const int w0 = (blockIdx.x & 63) * 2;
    // Stage 16 (h,w) rows of y2 (each 50*32 bf16, linear), c-padded 32->40 for banks.
    for (int i = t; i < 3200; i += 256) {
        int r = i / 200, cc = i - r * 200;
        int ih = r >> 2, iw = r & 3;
        int h = h0 - 1 + ih, w = w0 - 1 + iw;
        uint4 v = {0u, 0u, 0u, 0u};
        if ((unsigned)h < (unsigned)H_ && (unsigned)w < (unsigned)W_)
            v = *(const uint4*)(y2 + (h * W_ + w) * 1600 + cc * 8);
        int d = cc >> 2, cp = cc & 3;
        *(uint4*)(ys + (r * 50 + d) * 40 + cp * 8) = v;
    }
    __syncthreads();
    const int lane = t & 63, wid = t >> 6;
    const int ph = wid >> 1, pw = wid & 1;
    const int n = lane & 15, qk = lane >> 4;
    f32x4 acc[3][2] = {};
    for (int kd = 0; kd < 3; ++kd)
        for (int kh = 0; kh < 3; ++kh)
#pragma unroll
            for (int kw = 0; kw < 3; ++kw) {
                int tap = (kd * 3 + kh) * 3 + kw;
                const short8* wp = (const short8*)(wt + tap * 1024);
                short8 a0 = wp[n * 4 + qk];
                short8 a1 = wp[64 + n * 4 + qk];
                int rr = (ph + kh) * 4 + (pw + kw);
                int boff = (rr * 50 + kd + n) * 40 + qk * 8;
#pragma unroll
                for (int dt = 0; dt < 3; ++dt) {
                    short8 b = *(const short8*)(ys + boff + dt * 16 * 40);
                    acc[dt][0] = __builtin_amdgcn_mfma_f32_16x16x32_bf16(a0, b, acc[dt][0], 0, 0, 0);
                    acc[dt][1] = __builtin_amdgcn_mfma_f32_16x16x32_bf16(a1, b, acc[dt][1], 0, 0, 0);
                }
            }
    __syncthreads();
    float* obuf = (float*)lds;  // [c32][d48][pos4]
#pragma unroll
    for (int dt = 0; dt < 3; ++dt)
#pragma unroll
        for (int mh = 0; mh < 2; ++mh) {
            int d = dt * 16 + n;
#pragma unroll
            for (int r = 0; r < 4; ++r) {
                int co = mh * 16 + qk * 4 + r;
                obuf[(co * 48 + d) * 4 + wid] = acc[dt][mh][r];
            }
        }
    __syncthreads();
    const float rs = rsqrtf(1.f + 1e-5f);
    for (int i = t; i < 6144; i += 256) {
        int pw2 = i & 1, ph2 = (i >> 1) & 1;
        int rem = i >> 2;
        int d = rem % 48, c = rem / 48;
        float conv = obuf[(c * 48 + d) * 4 + ph2 * 2 + pw2];
        float val = conv * (bn2s[c] * rs) + bn2b[c];
        int addr = ((c * D_ + d) * H_ + h0 + ph2) * W_ + (w0 + pw2);
        out[addr] = fmaxf(val + x[addr], 0.f);
    }
}

extern "C" void kernel_launch(void* const* d_in, const int* in_sizes, int n_in,
                              void* d_out, int out_size, void* d_ws, size_t ws_size,
                              hipStream_t stream) {
    const float* x = (const float*)d_in[0];
    const float* g = (const float*)d_in[1];
    const float* wr = (const float*)d_in[2];
    const float* bn1s = (const float*)d_in[3];
    const float* bn1b = (const float*)d_in[4];
    const float* bn2s = (const float*)d_in[5];
    const float* bn2b = (const float*)d_in[6];
    float* out = (float*)d_out;
    char* ws = (char*)d_ws;

    float* xt = (float*)ws;                                   // 50,331,648 B (dead after scans)
    float* agg = (float*)(ws + 50331648);                     // 50,331,648 B
    unsigned short* y2 = (unsigned short*)ws;                 // aliases xt: 26,214,400 B
    unsigned short* wt = (unsigned short*)(ws + 100663296);   // 55,296 B

    k_transpose<<<2048, 256, 0, stream>>>(x, xt);
    k_scan<0><<<512, 256, 0, stream>>>(xt, g, agg);
    k_scan<1><<<512, 256, 0, stream>>>(xt, g, agg);
    k_scan<2><<<1024, 256, 0, stream>>>(xt, g, agg);
    k_scan<3><<<1024, 256, 0, stream>>>(xt, g, agg);
    k_wprep<<<108, 256, 0, stream>>>(wr, wt);
    k_prep<<<1024, 256, 0, stream>>>(agg, bn1s, bn1b, y2);
    k_conv<<<2048, 256, 0, stream>>>(y2, wt, x, bn2s, bn2b, out);
}

// Round 2
// 389.444 us; speedup vs baseline: 1.6144x; 1.6144x over previous
//
#include <hip/hip_runtime.h>

#define C_ 32
#define D_ 48
#define H_ 64
#define W_ 128
#define HW_ 8192

using short8 = __attribute__((ext_vector_type(8))) short;
using f32x4  = __attribute__((ext_vector_type(4))) float;

__device__ __forceinline__ unsigned short f2bf(float f) {
    unsigned u = __builtin_bit_cast(unsigned, f);
    unsigned r = (u + 0x7fffu + ((u >> 16) & 1u)) >> 16;
    return (unsigned short)r;
}
__device__ __forceinline__ float bf2f(unsigned short u) {
    return __builtin_bit_cast(float, ((unsigned)u) << 16);
}

// lane n <- lane n-1 (0 fill): wf_shr1
__device__ __forceinline__ float dpp_shr1z(float v) {
    int r = __builtin_amdgcn_update_dpp(0, __builtin_bit_cast(int, v), 0x138, 0xf, 0xf, true);
    return __builtin_bit_cast(float, r);
}
// lane n <- lane n+1 (0 fill): wf_shl1
__device__ __forceinline__ float dpp_shl1z(float v) {
    int r = __builtin_amdgcn_update_dpp(0, __builtin_bit_cast(int, v), 0x130, 0xf, 0xf, true);
    return __builtin_bit_cast(float, r);
}
// max over lanes 0..47 (lanes 48..63 must hold -big); result broadcast
__device__ __forceinline__ float wave_max48(float v) {
#define RMAX(ctrl)                                                                              \
    {                                                                                           \
        int t_ = __builtin_amdgcn_update_dpp(__builtin_bit_cast(int, v),                        \
                                             __builtin_bit_cast(int, v), ctrl, 0xf, 0xf, false);\
        v = fmaxf(v, __builtin_bit_cast(float, t_));                                            \
    }
    RMAX(0x111) RMAX(0x112) RMAX(0x114) RMAX(0x118) RMAX(0x142) RMAX(0x143)
#undef RMAX
    int m = __builtin_amdgcn_readlane(__builtin_bit_cast(int, v), 63);
    return __builtin_bit_cast(float, m);
}

// x[c][d][h][w] -> xt[c][h][w][d]
__global__ __launch_bounds__(256) void k_transpose(const float* __restrict__ x,
                                                   float* __restrict__ xt) {
    __shared__ float tile[48 * 129];
    const int t = threadIdx.x;
    const int c = blockIdx.x >> 6, h = blockIdx.x & 63;
    const float* xb = x + c * (D_ * HW_) + h * W_;
#pragma unroll
    for (int i = 0; i < 24; ++i) {
        int idx = i * 256 + t;
        int d = idx >> 7, w = idx & 127;
        tile[d * 129 + w] = xb[d * HW_ + w];
    }
    __syncthreads();
    float* xo = xt + ((c * H_ + h) * W_) * D_;
#pragma unroll
    for (int i = 0; i < 32; ++i) {
        int idx = i * 256 + t;
        int w = idx >> 6, dl = idx & 63;
        if (dl < 48) xo[w * D_ + dl] = tile[dl * 129 + w];
    }
}

// PHASE 0: fwd scans (W->agg1, H->agg2), plain bf16 write.
// PHASE 1: rev scans (W RMW agg1, H RMW agg2), max-combine.
// Blocks [0,512): W axis (T=128). Blocks [512,1536): H axis (T=64).
template <int PHASE>
__global__ __launch_bounds__(256) void k_scan(const float* __restrict__ xt,
                                              const float* __restrict__ g,
                                              unsigned short* __restrict__ agg1,
                                              unsigned short* __restrict__ agg2) {
    const int lane = threadIdx.x & 63;
    const int wid = threadIdx.x >> 6;
    const bool act = lane < 48;
    const bool isW = blockIdx.x < 512;
    const int L = isW ? blockIdx.x * 4 + wid : (blockIdx.x - 512) * 4 + wid;
    const int T = isW ? 128 : 64;
    const int idir = (isW ? 0 : 2) + PHASE;
    int base, ss, gb, gs;
    unsigned short* A;
    if (isW) {
        int c = L >> 6, h = L & 63;
        base = ((c * H_ + h) * W_) * D_;
        ss = D_;
        gb = ((idir * C_ + c) * 5) * HW_ + h * W_;
        gs = 1;
        A = agg1;
    } else {
        int c = L >> 7, w = L & 127;
        base = (c * HW_ + w) * D_;
        ss = W_ * D_;
        gb = ((idir * C_ + c) * 5) * HW_ + w;
        gs = W_;
        A = agg2;
    }

    float rpx[4], rw1[4], rw2[4], rw3[4], rw4[4], rav[4];

#define PREF(S, q)                                                              \
    {                                                                           \
        int qq_ = PHASE ? 0 : 0; (void)qq_;                                     \
        int qp_ = ((isW ? (PHASE ? 1 : 0) : (PHASE ? 1 : 0))) ? (T - 1 - (q)) : (q); \
        float xv_ = xt[base + qp_ * ss + lane];                                 \
        float c0_ = g[gb + qp_ * gs];                                           \
        float c1_ = g[gb + 8192 + qp_ * gs];                                    \
        float c2_ = g[gb + 16384 + qp_ * gs];                                   \
        float c3_ = g[gb + 24576 + qp_ * gs];                                   \
        float c4_ = g[gb + 32768 + qp_ * gs];                                   \
        if (PHASE) rav[S] = bf2f(A[base + qp_ * ss + lane]);                    \
        float s_ = fabsf(c0_) + fabsf(c1_) + fabsf(c2_) + fabsf(c3_) + fabsf(c4_); \
        float rn_ = __builtin_amdgcn_rcpf(fmaxf(s_, 1e-12f));                   \
        rpx[S] = c0_ * rn_ * xv_;                                               \
        rw1[S] = c1_ * rn_;                                                     \
        rw2[S] = c2_ * rn_;                                                     \
        rw3[S] = c3_ * rn_;                                                     \
        rw4[S] = c4_ * rn_;                                                     \
    }

    float prev;
    {
        int qq = PHASE ? (T - 1) : 0;  // REV == PHASE
        float xv = xt[base + qq * ss + lane];
        prev = xv;
        float o = prev;
        if (PHASE) o = fmaxf(o, bf2f(A[base + qq * ss + lane]));
        if (act) A[base + qq * ss + lane] = f2bf(o);
    }
    PREF(1, 1) PREF(2, 2) PREF(3, 3) PREF(0, 4)

#define STEP(S, p_)                                                             \
    {                                                                           \
        float w1_ = rw1[S], w2_ = rw2[S], w3_ = rw3[S], w4_ = rw4[S];           \
        float px_ = rpx[S], av_ = rav[S];                                       \
        if ((p_) + 4 < T) PREF(S, (p_) + 4);                                    \
        float pz_ = act ? prev : 0.f;                                           \
        float dm_ = dpp_shr1z(pz_);                                             \
        float dp_ = dpp_shl1z(pz_);                                             \
        float mi_ = act ? prev : -3.4e38f;                                      \
        float mx_ = wave_max48(mi_);                                            \
        float a_ = fmaf(w2_, dm_, px_);                                         \
        a_ = fmaf(w3_, dp_, a_);                                                \
        a_ = fmaf(w1_, prev, a_);                                               \
        a_ = fmaf(w4_, mx_, a_);                                                \
        int qq_ = PHASE ? (T - 1 - (p_)) : (p_);                                \
        float o_ = PHASE ? fmaxf(a_, av_) : a_;                                 \
        if (act) A[base + qq_ * ss + lane] = f2bf(o_);                          \
        prev = a_;                                                              \
    }

    int p = 1;
    for (; p + 3 < T; p += 4) {
        STEP(1, p) STEP(2, p + 1) STEP(3, p + 2) STEP(0, p + 3)
    }
    // (T-1) % 4 == 3 for T in {64,128}: exactly three remainder steps, slots 1,2,3
    STEP(1, p) STEP(2, p + 1) STEP(3, p + 2)
#undef STEP
#undef PREF
}

// max(agg1,agg2) -> BN1 -> ReLU -> y2[h][w][dpad(50)][c] bf16 (d-pad zeros)
__global__ __launch_bounds__(256) void k_prep(const unsigned short* __restrict__ agg1,
                                              const unsigned short* __restrict__ agg2,
                                              const float* __restrict__ bn1s,
                                              const float* __restrict__ bn1b,
                                              unsigned short* __restrict__ y2) {
    __shared__ float L[48 * 33];
    __shared__ float s_inv[32], s_b[32];
    const int t = threadIdx.x;
    if (t < 32) {
        s_inv[t] = bn1s[t] * rsqrtf(1.f + 1e-5f);
        s_b[t] = bn1b[t];
    }
    __syncthreads();
    const int h = blockIdx.x >> 4;
    const int w0 = (blockIdx.x & 15) * 8;
    for (int wi = 0; wi < 8; ++wi) {
        int w = w0 + wi;
#pragma unroll
        for (int i = 0; i < 6; ++i) {
            int idx = i * 256 + t;  // 0..1535
            int c = idx / 48, d = idx - c * 48;
            int off = ((c * H_ + h) * W_ + w) * D_ + d;
            float v = fmaxf(bf2f(agg1[off]), bf2f(agg2[off]));
            L[d * 33 + c] = fmaxf(v * s_inv[c] + s_b[c], 0.f);
        }
        __syncthreads();
#pragma unroll
        for (int i = 0; i < 7; ++i) {
            int idx = i * 256 + t;
            if (idx < 1600) {
                int c = idx & 31, dp = idx >> 5;
                float v = (dp == 0 || dp == 49) ? 0.f : L[(dp - 1) * 33 + c];
                y2[(h * W_ + w) * 1600 + dp * 32 + c] = f2bf(v);
            }
        }
        __syncthreads();
    }
}

// w_refine[co][ci][tap] -> wt[tap][co][ci] bf16
__global__ __launch_bounds__(256) void k_wprep(const float* __restrict__ wr,
                                               unsigned short* __restrict__ wt) {
    int idx = blockIdx.x * 256 + threadIdx.x;  // 27648 total
    int ci = idx & 31, co = (idx >> 5) & 31, tap = idx >> 10;
    wt[(tap * 32 + co) * 32 + ci] = f2bf(wr[(co * 32 + ci) * 27 + tap]);
}

// Implicit-GEMM conv: M=co(2x16), N=w(16), K=ci(32). Wave: 2 co-tiles x w16 x 12 d.
// Block: w32 x d24 at one h (4 waves). Grid: 64h x 4wspan x 2dhalf = 512 blocks.
__global__ __launch_bounds__(256) void k_conv(const unsigned short* __restrict__ y2,
                                              const unsigned short* __restrict__ wt,
                                              const float* __restrict__ x,
                                              const float* __restrict__ bn2s,
                                              const float* __restrict__ bn2b,
                                              float* __restrict__ out) {
    const int t = threadIdx.x;
    const int lane = t & 63, wid = t >> 6;
    const int h = blockIdx.x >> 3;
    const int wspan = (blockIdx.x >> 1) & 3;
    const int dhalf = blockIdx.x & 1;
    const int w16 = wspan * 32 + (wid & 1) * 16;
    const int d0 = dhalf * 24 + (wid >> 1) * 12;
    const int n = lane & 15, kg = lane >> 4;
    f32x4 acc[12][2] = {};
    for (int kh = 0; kh < 3; ++kh) {
        int hin = h + kh - 1;
        if ((unsigned)hin >= (unsigned)H_) continue;
#pragma unroll
        for (int kd = 0; kd < 3; ++kd)
#pragma unroll
            for (int kw = 0; kw < 3; ++kw) {
                int tap = (kd * 3 + kh) * 3 + kw;
                short8 A0 = *(const short8*)(wt + (tap * 32 + n) * 32 + kg * 8);
                short8 A1 = *(const short8*)(wt + (tap * 32 + 16 + n) * 32 + kg * 8);
                int win = w16 + n + kw - 1;
                bool ok = (unsigned)win < (unsigned)W_;
                const unsigned short* bp =
                    y2 + (hin * W_ + win) * 1600 + (d0 + kd) * 32 + kg * 8;
#pragma unroll
                for (int dd = 0; dd < 12; ++dd) {
                    uint4 v = make_uint4(0, 0, 0, 0);
                    if (ok) v = *(const uint4*)(bp + dd * 32);
                    short8 b = __builtin_bit_cast(short8, v);
                    acc[dd][0] = __builtin_amdgcn_mfma_f32_16x16x32_bf16(A0, b, acc[dd][0], 0, 0, 0);
                    acc[dd][1] = __builtin_amdgcn_mfma_f32_16x16x32_bf16(A1, b, acc[dd][1], 0, 0, 0);
                }
            }
    }
    const float rs = rsqrtf(1.f + 1e-5f);
#pragma unroll
    for (int ct = 0; ct < 2; ++ct)
#pragma unroll
        for (int r = 0; r < 4; ++r) {
            int co = ct * 16 + kg * 4 + r;
            float sc = bn2s[co] * rs, bi = bn2b[co];
#pragma unroll
            for (int dd = 0; dd < 12; ++dd) {
                int d = d0 + dd;
                int addr = ((co * D_ + d) * H_ + h) * W_ + w16 + n;
                float val = acc[dd][ct][r] * sc + bi;
                out[addr] = fmaxf(val + x[addr], 0.f);
            }
        }
}

extern "C" void kernel_launch(void* const* d_in, const int* in_sizes, int n_in,
                              void* d_out, int out_size, void* d_ws, size_t ws_size,
                              hipStream_t stream) {
    const float* x = (const float*)d_in[0];
    const float* g = (const float*)d_in[1];
    const float* wr = (const float*)d_in[2];
    const float* bn1s = (const float*)d_in[3];
    const float* bn1b = (const float*)d_in[4];
    const float* bn2s = (const float*)d_in[5];
    const float* bn2b = (const float*)d_in[6];
    float* out = (float*)d_out;
    char* ws = (char*)d_ws;

    float* xt = (float*)ws;                                  // [0, 50331648)
    unsigned short* agg1 = (unsigned short*)(ws + 50331648); // 25165824 B
    unsigned short* agg2 = (unsigned short*)(ws + 75497472); // 25165824 B
    unsigned short* wt = (unsigned short*)(ws + 100663296);  // 55296 B
    unsigned short* y2 = (unsigned short*)ws;                // aliases xt (dead after scans)

    k_transpose<<<2048, 256, 0, stream>>>(x, xt);
    k_scan<0><<<1536, 256, 0, stream>>>(xt, g, agg1, agg2);
    k_scan<1><<<1536, 256, 0, stream>>>(xt, g, agg1, agg2);
    k_wprep<<<108, 256, 0, stream>>>(wr, wt);
    k_prep<<<1024, 256, 0, stream>>>(agg1, agg2, bn1s, bn1b, y2);
    k_conv<<<512, 256, 0, stream>>>(y2, wt, x, bn2s, bn2b, out);
}

// Round 3
// 359.212 us; speedup vs baseline: 1.7502x; 1.0842x over previous
//
#include <hip/hip_runtime.h>

#define C_ 32
#define D_ 48
#define H_ 64
#define W_ 128
#define HW_ 8192

using short8 = __attribute__((ext_vector_type(8))) short;
using f32x4  = __attribute__((ext_vector_type(4))) float;

__device__ __forceinline__ unsigned short f2bf(float f) {
    unsigned u = __builtin_bit_cast(unsigned, f);
    unsigned r = (u + 0x7fffu + ((u >> 16) & 1u)) >> 16;
    return (unsigned short)r;
}
__device__ __forceinline__ float bf2f(unsigned short u) {
    return __builtin_bit_cast(float, ((unsigned)u) << 16);
}
__device__ __forceinline__ float f16tof(unsigned short u) {
    return (float)__builtin_bit_cast(_Float16, u);
}

// lane n <- lane n-1 (0 fill): wf_shr1
__device__ __forceinline__ float dpp_shr1z(float v) {
    int r = __builtin_amdgcn_update_dpp(0, __builtin_bit_cast(int, v), 0x138, 0xf, 0xf, true);
    return __builtin_bit_cast(float, r);
}
// lane n <- lane n+1 (0 fill): wf_shl1
__device__ __forceinline__ float dpp_shl1z(float v) {
    int r = __builtin_amdgcn_update_dpp(0, __builtin_bit_cast(int, v), 0x130, 0xf, 0xf, true);
    return __builtin_bit_cast(float, r);
}
// max over lanes 0..47 (lanes 48..63 must hold -big); result broadcast
__device__ __forceinline__ float wave_max48(float v) {
#define RMAX(ctrl)                                                                              \
    {                                                                                           \
        int t_ = __builtin_amdgcn_update_dpp(__builtin_bit_cast(int, v),                        \
                                             __builtin_bit_cast(int, v), ctrl, 0xf, 0xf, false);\
        v = fmaxf(v, __builtin_bit_cast(float, t_));                                            \
    }
    RMAX(0x111) RMAX(0x112) RMAX(0x114) RMAX(0x118) RMAX(0x142) RMAX(0x143)
#undef RMAX
    int m = __builtin_amdgcn_readlane(__builtin_bit_cast(int, v), 63);
    return __builtin_bit_cast(float, m);
}

// x[c][d][h][w] fp32 -> xtb[c][h][w][d] bf16
__global__ __launch_bounds__(256) void k_transpose(const float* __restrict__ x,
                                                   unsigned short* __restrict__ xtb) {
    __shared__ float tile[48 * 129];
    const int t = threadIdx.x;
    const int c = blockIdx.x >> 6, h = blockIdx.x & 63;
    const float* xb = x + c * (D_ * HW_) + h * W_;
#pragma unroll
    for (int i = 0; i < 24; ++i) {
        int idx = i * 256 + t;
        int d = idx >> 7, w = idx & 127;
        tile[d * 129 + w] = xb[d * HW_ + w];
    }
    __syncthreads();
    unsigned short* xo = xtb + ((c * H_ + h) * W_) * D_;
#pragma unroll
    for (int i = 0; i < 32; ++i) {
        int idx = i * 256 + t;
        int w = idx >> 6, dl = idx & 63;
        if (dl < 48) xo[w * D_ + dl] = f2bf(tile[dl * 129 + w]);
    }
}

// g[dir][c][i][h][w] -> gq entries of 8 ushorts: 5 normalized fp16 weights + pad.
// dirs 0,1 entry order [c][h*128+w]; dirs 2,3 entry order [c][w*64+h].
__global__ __launch_bounds__(256) void k_gprep(const float* __restrict__ g,
                                               unsigned short* __restrict__ gq) {
    int e = blockIdx.x * 256 + threadIdx.x;  // 1,048,576 entries
    int dir = e >> 18;
    int r = e & 262143;
    int c = r >> 13;
    int pos = r & 8191;
    int pin = (dir < 2) ? pos : ((pos & 63) * W_ + (pos >> 6));
    const float* gp = g + ((dir * C_ + c) * 5) * HW_ + pin;
    float c0 = gp[0], c1 = gp[HW_], c2 = gp[2 * HW_], c3 = gp[3 * HW_], c4 = gp[4 * HW_];
    float s = fabsf(c0) + fabsf(c1) + fabsf(c2) + fabsf(c3) + fabsf(c4);
    float rn = __builtin_amdgcn_rcpf(fmaxf(s, 1e-12f));
    unsigned h0 = __builtin_bit_cast(unsigned short, (_Float16)(c0 * rn));
    unsigned h1 = __builtin_bit_cast(unsigned short, (_Float16)(c1 * rn));
    unsigned h2 = __builtin_bit_cast(unsigned short, (_Float16)(c2 * rn));
    unsigned h3 = __builtin_bit_cast(unsigned short, (_Float16)(c3 * rn));
    unsigned h4 = __builtin_bit_cast(unsigned short, (_Float16)(c4 * rn));
    uint4 o = {h0 | (h1 << 16), h2 | (h3 << 16), h4, 0u};
    ((uint4*)gq)[e] = o;
}

// One directional pass over a line. xb/ab are per-lane bases; gq is line base (shorts).
template <int T, int SS, bool REV>
__device__ __forceinline__ void scan_pass(const unsigned short* __restrict__ xb,
                                          const unsigned short* __restrict__ gq,
                                          unsigned short* __restrict__ ab, bool act) {
    constexpr int PF = 8;
    float xs[PF], as[PF];
    uint4 gs[PF];
    float prev;
    {
        constexpr int q0 = REV ? (T - 1) : 0;
        prev = bf2f(xb[q0 * SS]);
        float o = prev;
        if (REV) o = fmaxf(o, bf2f(ab[q0 * SS]));
        if (act) ab[q0 * SS] = f2bf(o);
    }
#pragma unroll
    for (int i = 0; i < PF; ++i) {
        int q = REV ? (T - 2 - i) : (1 + i);
        xs[i] = bf2f(xb[q * SS]);
        gs[i] = *(const uint4*)(gq + q * 8);
        as[i] = REV ? bf2f(ab[q * SS]) : 0.f;
    }
    auto step = [&](int pc, int slot) {
        float xv = xs[slot];
        uint4 u = gs[slot];
        float av = as[slot];
        int pn = pc + PF;
        if (pn < T) {
            int qn = REV ? (T - 1 - pn) : pn;
            xs[slot] = bf2f(xb[qn * SS]);
            gs[slot] = *(const uint4*)(gq + qn * 8);
            if (REV) as[slot] = bf2f(ab[qn * SS]);
        }
        float w0 = f16tof((unsigned short)(u.x & 0xffffu));
        float w1 = f16tof((unsigned short)(u.x >> 16));
        float w2 = f16tof((unsigned short)(u.y & 0xffffu));
        float w3 = f16tof((unsigned short)(u.y >> 16));
        float w4 = f16tof((unsigned short)(u.z & 0xffffu));
        float pz = act ? prev : 0.f;
        float dm = dpp_shr1z(pz);
        float dp = dpp_shl1z(pz);
        float mi = act ? prev : -3.4e38f;
        float mx = wave_max48(mi);
        float a = fmaf(w1, prev, w0 * xv);
        a = fmaf(w2, dm, a);
        a = fmaf(w3, dp, a);
        a = fmaf(w4, mx, a);
        float o = REV ? fmaxf(a, av) : a;
        int qq = REV ? (T - 1 - pc) : pc;
        if (act) ab[qq * SS] = f2bf(o);
        prev = a;
    };
    int p = 1;
#pragma unroll 1
    for (; p + PF <= T; p += PF) {
#pragma unroll
        for (int i = 0; i < PF; ++i) step(p + i, i);
    }
#pragma unroll
    for (int i = 0; i < PF; ++i)
        if (p + i < T) step(p + i, i);
}

__global__ __launch_bounds__(256) void k_scanW(const unsigned short* __restrict__ xtb,
                                               const unsigned short* __restrict__ gq,
                                               unsigned short* __restrict__ agg1) {
    const int lane = threadIdx.x & 63;
    const int wid = threadIdx.x >> 6;
    const int L = blockIdx.x * 4 + wid;  // 0..2047
    const int c = L >> 6, h = L & 63;
    const int dl = (lane < 48) ? lane : 47;
    const bool act = lane < 48;
    const int base = ((c * H_ + h) * W_) * D_ + dl;
    const unsigned short* xb = xtb + base;
    unsigned short* ab = agg1 + base;
    const unsigned short* g0 = gq + (unsigned)((0 * C_ + c) * HW_ + h * W_) * 8;
    const unsigned short* g1 = gq + (unsigned)((1 * C_ + c) * HW_ + h * W_) * 8;
    scan_pass<W_, D_, false>(xb, g0, ab, act);
    __builtin_amdgcn_s_waitcnt(0);
    scan_pass<W_, D_, true>(xb, g1, ab, act);
}

__global__ __launch_bounds__(256) void k_scanH(const unsigned short* __restrict__ xtb,
                                               const unsigned short* __restrict__ gq,
                                               unsigned short* __restrict__ agg2) {
    const int lane = threadIdx.x & 63;
    const int wid = threadIdx.x >> 6;
    const int L = blockIdx.x * 4 + wid;  // 0..4095
    const int c = L >> 7, w = L & 127;
    const int dl = (lane < 48) ? lane : 47;
    const bool act = lane < 48;
    const int base = (c * HW_ + w) * D_ + dl;
    const unsigned short* xb = xtb + base;
    unsigned short* ab = agg2 + base;
    const unsigned short* g2 = gq + (unsigned)((2 * C_ + c) * HW_ + w * H_) * 8;
    const unsigned short* g3 = gq + (unsigned)((3 * C_ + c) * HW_ + w * H_) * 8;
    scan_pass<H_, W_ * D_, false>(xb, g2, ab, act);
    __builtin_amdgcn_s_waitcnt(0);
    scan_pass<H_, W_ * D_, true>(xb, g3, ab, act);
}

// max(agg1,agg2) -> BN1 -> ReLU -> y2p[h+1][d+1][w+1][c] bf16 (pads pre-zeroed)
__global__ __launch_bounds__(256) void k_prep(const unsigned short* __restrict__ agg1,
                                              const unsigned short* __restrict__ agg2,
                                              const float* __restrict__ bn1s,
                                              const float* __restrict__ bn1b,
                                              unsigned short* __restrict__ y2p) {
    __shared__ float L[48 * 33];
    __shared__ float s_inv[32], s_b[32];
    const int t = threadIdx.x;
    if (t < 32) {
        s_inv[t] = bn1s[t] * rsqrtf(1.f + 1e-5f);
        s_b[t] = bn1b[t];
    }
    __syncthreads();
    const int h = blockIdx.x >> 4;
    const int w0 = (blockIdx.x & 15) * 8;
    for (int wi = 0; wi < 8; ++wi) {
        int w = w0 + wi;
#pragma unroll
        for (int i = 0; i < 6; ++i) {
            int idx = i * 256 + t;  // 0..1535
            int c = idx / 48, d = idx - c * 48;
            int off = ((c * H_ + h) * W_ + w) * D_ + d;
            float v = fmaxf(bf2f(agg1[off]), bf2f(agg2[off]));
            L[d * 33 + c] = fmaxf(v * s_inv[c] + s_b[c], 0.f);
        }
        __syncthreads();
        unsigned short* yb = y2p + (((h + 1) * 50) * 130 + (w + 1)) * 32;
#pragma unroll
        for (int i = 0; i < 6; ++i) {
            int idx = i * 256 + t;
            int c = idx & 31, d = idx >> 5;
            yb[(d + 1) * (130 * 32) + c] = f2bf(L[d * 33 + c]);
        }
        __syncthreads();
    }
}

// w_refine[co][ci][tap] -> wt[tap][co][ci] bf16
__global__ __launch_bounds__(256) void k_wprep(const float* __restrict__ wr,
                                               unsigned short* __restrict__ wt) {
    int idx = blockIdx.x * 256 + threadIdx.x;  // 27648
    int ci = idx & 31, co = (idx >> 5) & 31, tap = idx >> 10;
    wt[(tap * 32 + co) * 32 + ci] = f2bf(wr[(co * 32 + ci) * 27 + tap]);
}

// Implicit-GEMM conv: M=co(2x16), N=w(16), K=ci(32). Wave: 2 co-tiles x w16 x 6 d.
// Fully padded input -> no branches; B-fragment loads are lane-contiguous 1 KB.
__global__ __launch_bounds__(256) void k_conv(const unsigned short* __restrict__ y2p,
                                              const unsigned short* __restrict__ wt,
                                              const float* __restrict__ x,
                                              const float* __restrict__ bn2s,
                                              const float* __restrict__ bn2b,
                                              float* __restrict__ out) {
    const int t = threadIdx.x;
    const int lane = t & 63, wid = t >> 6;
    const int h = blockIdx.x >> 4;
    const int w16 = ((blockIdx.x >> 1) & 7) * 16;
    const int d0 = (blockIdx.x & 1) * 24 + wid * 6;
    const int n = lane & 15, kg = lane >> 4;
    f32x4 acc[6][2] = {};
#pragma unroll
    for (int kh = 0; kh < 3; ++kh) {
        const unsigned short* yh = y2p + (h + kh) * (50 * 130 * 32);
#pragma unroll
        for (int kd = 0; kd < 3; ++kd)
#pragma unroll
            for (int kw = 0; kw < 3; ++kw) {
                int tap = (kd * 3 + kh) * 3 + kw;
                short8 A0 = *(const short8*)(wt + (tap * 32 + n) * 32 + kg * 8);
                short8 A1 = *(const short8*)(wt + (tap * 32 + 16 + n) * 32 + kg * 8);
                const unsigned short* bp = yh + ((d0 + kd) * 130 + (w16 + n + kw)) * 32 + kg * 8;
#pragma unroll
                for (int dd = 0; dd < 6; ++dd) {
                    short8 b = *(const short8*)(bp + dd * (130 * 32));
                    acc[dd][0] = __builtin_amdgcn_mfma_f32_16x16x32_bf16(A0, b, acc[dd][0], 0, 0, 0);
                    acc[dd][1] = __builtin_amdgcn_mfma_f32_16x16x32_bf16(A1, b, acc[dd][1], 0, 0, 0);
                }
            }
    }
    const float rs = rsqrtf(1.f + 1e-5f);
#pragma unroll
    for (int ct = 0; ct < 2; ++ct)
#pragma unroll
        for (int r = 0; r < 4; ++r) {
            int co = ct * 16 + kg * 4 + r;
            float sc = bn2s[co] * rs, bi = bn2b[co];
#pragma unroll
            for (int dd = 0; dd < 6; ++dd) {
                int d = d0 + dd;
                int addr = ((co * D_ + d) * H_ + h) * W_ + w16 + n;
                float val = acc[dd][ct][r] * sc + bi;
                out[addr] = fmaxf(val + x[addr], 0.f);
            }
        }
}

extern "C" void kernel_launch(void* const* d_in, const int* in_sizes, int n_in,
                              void* d_out, int out_size, void* d_ws, size_t ws_size,
                              hipStream_t stream) {
    const float* x = (const float*)d_in[0];
    const float* g = (const float*)d_in[1];
    const float* wr = (const float*)d_in[2];
    const float* bn1s = (const float*)d_in[3];
    const float* bn1b = (const float*)d_in[4];
    const float* bn2s = (const float*)d_in[5];
    const float* bn2b = (const float*)d_in[6];
    float* out = (float*)d_out;
    char* ws = (char*)d_ws;

    unsigned short* xtb = (unsigned short*)ws;               // 25,165,824 B (dead after scans)
    unsigned short* y2p = (unsigned short*)ws;               // 27,456,000 B (aliases xtb)
    unsigned short* agg1 = (unsigned short*)(ws + 33554432); // 25,165,824 B
    unsigned short* agg2 = (unsigned short*)(ws + 58720256); // 25,165,824 B
    unsigned short* gq = (unsigned short*)(ws + 83886080);   // 16,777,216 B
    unsigned short* wt = (unsigned short*)(ws + 100663296);  // 55,296 B -> total 100,718,592

    k_transpose<<<2048, 256, 0, stream>>>(x, xtb);
    k_gprep<<<4096, 256, 0, stream>>>(g, gq);
    k_scanW<<<512, 256, 0, stream>>>(xtb, gq, agg1);
    k_scanH<<<1024, 256, 0, stream>>>(xtb, gq, agg2);
    k_wprep<<<108, 256, 0, stream>>>(wr, wt);
    hipMemsetAsync(y2p, 0, 27456000, stream);
    k_prep<<<1024, 256, 0, stream>>>(agg1, agg2, bn1s, bn1b, y2p);
    k_conv<<<1024, 256, 0, stream>>>(y2p, wt, x, bn2s, bn2b, out);
}

// Round 4
// 312.543 us; speedup vs baseline: 2.0116x; 1.1493x over previous
//
#include <hip/hip_runtime.h>

#define C_ 32
#define D_ 48
#define H_ 64
#define W_ 128
#define HW_ 8192

using short8 = __attribute__((ext_vector_type(8))) short;
using f32x4  = __attribute__((ext_vector_type(4))) float;

__device__ __forceinline__ unsigned short f2bf(float f) {
    unsigned u = __builtin_bit_cast(unsigned, f);
    unsigned r = (u + 0x7fffu + ((u >> 16) & 1u)) >> 16;
    return (unsigned short)r;
}
__device__ __forceinline__ float bf2f(unsigned short u) {
    return __builtin_bit_cast(float, ((unsigned)u) << 16);
}
__device__ __forceinline__ float f16tof(unsigned short u) {
    return (float)__builtin_bit_cast(_Float16, u);
}
__device__ __forceinline__ const unsigned short* uni_ptr(const unsigned short* p) {
    unsigned long long v = (unsigned long long)p;
    unsigned lo = __builtin_amdgcn_readfirstlane((unsigned)v);
    unsigned hi = __builtin_amdgcn_readfirstlane((unsigned)(v >> 32));
    return (const unsigned short*)(((unsigned long long)hi << 32) | lo);
}

// lane n <- lane n-1 (0 fill): wf_shr1
__device__ __forceinline__ float dpp_shr1z(float v) {
    int r = __builtin_amdgcn_update_dpp(0, __builtin_bit_cast(int, v), 0x138, 0xf, 0xf, true);
    return __builtin_bit_cast(float, r);
}
// lane n <- lane n+1 (0 fill): wf_shl1
__device__ __forceinline__ float dpp_shl1z(float v) {
    int r = __builtin_amdgcn_update_dpp(0, __builtin_bit_cast(int, v), 0x130, 0xf, 0xf, true);
    return __builtin_bit_cast(float, r);
}
// max over lanes 0..47 (lanes 48..63 must hold -big); result broadcast
__device__ __forceinline__ float wave_max48(float v) {
#define RMAX(ctrl)                                                                              \
    {                                                                                           \
        int t_ = __builtin_amdgcn_update_dpp(__builtin_bit_cast(int, v),                        \
                                             __builtin_bit_cast(int, v), ctrl, 0xf, 0xf, false);\
        v = fmaxf(v, __builtin_bit_cast(float, t_));                                            \
    }
    RMAX(0x111) RMAX(0x112) RMAX(0x114) RMAX(0x118) RMAX(0x142) RMAX(0x143)
#undef RMAX
    int m = __builtin_amdgcn_readlane(__builtin_bit_cast(int, v), 63);
    return __builtin_bit_cast(float, m);
}

__device__ __forceinline__ uint4 pack5(float c0, float c1, float c2, float c3, float c4) {
    float s = fabsf(c0) + fabsf(c1) + fabsf(c2) + fabsf(c3) + fabsf(c4);
    float rn = __builtin_amdgcn_rcpf(fmaxf(s, 1e-12f));
    unsigned h0 = __builtin_bit_cast(unsigned short, (_Float16)(c0 * rn));
    unsigned h1 = __builtin_bit_cast(unsigned short, (_Float16)(c1 * rn));
    unsigned h2 = __builtin_bit_cast(unsigned short, (_Float16)(c2 * rn));
    unsigned h3 = __builtin_bit_cast(unsigned short, (_Float16)(c3 * rn));
    unsigned h4 = __builtin_bit_cast(unsigned short, (_Float16)(c4 * rn));
    return uint4{h0 | (h1 << 16), h2 | (h3 << 16), h4, 0u};
}

// Fused front end:
//  blocks [0,2048):     x[c][d][h][w] fp32 -> xtb[c][h][w][d] bf16
//  blocks [2048,4096):  gprep dirs 0,1 (coalesced): gq entry = 5 fp16 L1-normed weights
//  blocks [4096,4352):  gprep dirs 2,3 via LDS transpose, entries in [c][w*64+h] order
//  blocks [4352,4460):  w_refine[co][ci][tap] -> wt[tap][co][ci] bf16
__global__ __launch_bounds__(256) void k_front(const float* __restrict__ x,
                                               const float* __restrict__ g,
                                               const float* __restrict__ wr,
                                               unsigned short* __restrict__ xtb,
                                               unsigned short* __restrict__ gq,
                                               unsigned short* __restrict__ wt) {
    __shared__ float sbuf[10560];
    const int t = threadIdx.x;
    const int bid = blockIdx.x;
    if (bid < 2048) {
        const int c = bid >> 6, h = bid & 63;
        const float* xb = x + c * (D_ * HW_) + h * W_;
#pragma unroll
        for (int i = 0; i < 24; ++i) {
            int idx = i * 256 + t;
            int d = idx >> 7, w = idx & 127;
            sbuf[d * 129 + w] = xb[d * HW_ + w];
        }
        __syncthreads();
        unsigned short* xo = xtb + ((c * H_ + h) * W_) * D_;
#pragma unroll
        for (int i = 0; i < 32; ++i) {
            int idx = i * 256 + t;
            int w = idx >> 6, dl = idx & 63;
            if (dl < 48) xo[w * D_ + dl] = f2bf(sbuf[dl * 129 + w]);
        }
    } else if (bid < 4096) {
        int e = (bid - 2048) * 256 + t;  // 0..524287, dirs 0,1
        int dir = e >> 18;
        int c = (e >> 13) & 31;
        int pos = e & 8191;
        const float* gp = g + ((dir * C_ + c) * 5) * HW_ + pos;
        ((uint4*)gq)[e] = pack5(gp[0], gp[HW_], gp[2 * HW_], gp[3 * HW_], gp[4 * HW_]);
    } else if (bid < 4352) {
        int b = bid - 4096;
        int d2 = b >> 7, c = (b >> 2) & 31, w0 = (b & 3) * 32;
        const float* gp = g + (((d2 + 2) * C_ + c) * 5) * HW_;
#pragma unroll
        for (int k = 0; k < 40; ++k) {
            int j = k * 256 + t;  // 10240 = 5 x 64h x 32w
            int i = j >> 11, r = j & 2047;
            int h = r >> 5, wl = r & 31;
            sbuf[i * 2112 + h * 33 + wl] = gp[i * HW_ + h * W_ + w0 + wl];
        }
        __syncthreads();
        uint4* gqo = (uint4*)gq + ((d2 + 2) * C_ + c) * HW_;
#pragma unroll
        for (int k = 0; k < 8; ++k) {
            int j = k * 256 + t;  // 2048 = 32w x 64h
            int wl = j >> 6, h = j & 63;
            int s = h * 33 + wl;
            gqo[(w0 + wl) * 64 + h] = pack5(sbuf[s], sbuf[2112 + s], sbuf[4224 + s],
                                            sbuf[6336 + s], sbuf[8448 + s]);
        }
    } else {
        int idx = (bid - 4352) * 256 + t;  // 27648
        int ci = idx & 31, co = (idx >> 5) & 31, tap = idx >> 10;
        wt[(tap * 32 + co) * 32 + ci] = f2bf(wr[(co * 32 + ci) * 27 + tap]);
    }
}

// One directional pass over a line. xb/ab per-lane bases; gq wave-uniform line base.
template <int T, int SS, bool REV>
__device__ __forceinline__ void scan_pass(const unsigned short* __restrict__ xb,
                                          const unsigned short* __restrict__ gq,
                                          unsigned short* __restrict__ ab, bool act) {
    constexpr int PF = 8;
    float xs[PF], as[PF];
    uint4 gs[PF];
    float prev;
    {
        constexpr int q0 = REV ? (T - 1) : 0;
        prev = bf2f(xb[q0 * SS]);
        float o = prev;
        if (REV) o = fmaxf(o, bf2f(ab[q0 * SS]));
        if (act) ab[q0 * SS] = f2bf(o);
    }
#pragma unroll
    for (int i = 0; i < PF; ++i) {
        int q = REV ? (T - 2 - i) : (1 + i);
        xs[i] = bf2f(xb[q * SS]);
        gs[i] = *(const uint4*)(gq + q * 8);
        as[i] = REV ? bf2f(ab[q * SS]) : 0.f;
    }
    auto step = [&](int pc, int slot) {
        float xv = xs[slot];
        uint4 u = gs[slot];
        float av = as[slot];
        int pn = pc + PF;
        if (pn < T) {
            int qn = REV ? (T - 1 - pn) : pn;
            xs[slot] = bf2f(xb[qn * SS]);
            gs[slot] = *(const uint4*)(gq + qn * 8);
            if (REV) as[slot] = bf2f(ab[qn * SS]);
        }
        float w0 = f16tof((unsigned short)(u.x & 0xffffu));
        float w1 = f16tof((unsigned short)(u.x >> 16));
        float w2 = f16tof((unsigned short)(u.y & 0xffffu));
        float w3 = f16tof((unsigned short)(u.y >> 16));
        float w4 = f16tof((unsigned short)(u.z & 0xffffu));
        float pz = act ? prev : 0.f;
        float dm = dpp_shr1z(pz);
        float dp = dpp_shl1z(pz);
        float mi = act ? prev : -3.4e38f;
        float mx = wave_max48(mi);
        float a = fmaf(w1, prev, w0 * xv);
        a = fmaf(w2, dm, a);
        a = fmaf(w3, dp, a);
        a = fmaf(w4, mx, a);
        float o = REV ? fmaxf(a, av) : a;
        int qq = REV ? (T - 1 - pc) : pc;
        if (act) ab[qq * SS] = f2bf(o);
        prev = a;
    };
    int p = 1;
#pragma unroll 1
    for (; p + PF <= T; p += PF) {
#pragma unroll
        for (int i = 0; i < PF; ++i) step(p + i, i);
    }
#pragma unroll
    for (int i = 0; i < PF; ++i)
        if (p + i < T) step(p + i, i);
}

// blocks [0,512): W axis lines; [512,1536): H axis lines. fwd then rev (max-combine).
__global__ __launch_bounds__(256) void k_scan(const unsigned short* __restrict__ xtb,
                                              const unsigned short* __restrict__ gq,
                                              unsigned short* __restrict__ agg1,
                                              unsigned short* __restrict__ agg2) {
    const int lane = threadIdx.x & 63;
    const int wid = threadIdx.x >> 6;
    const int dl = (lane < 48) ? lane : 47;
    const bool act = lane < 48;
    if (blockIdx.x < 512) {
        const int L = blockIdx.x * 4 + wid;  // 0..2047
        const int c = L >> 6, h = L & 63;
        const int base = ((c * H_ + h) * W_) * D_ + dl;
        const unsigned short* xb = xtb + base;
        unsigned short* ab = agg1 + base;
        const unsigned short* g0 = uni_ptr(gq + (unsigned)((0 * C_ + c) * HW_ + h * W_) * 8);
        const unsigned short* g1 = uni_ptr(gq + (unsigned)((1 * C_ + c) * HW_ + h * W_) * 8);
        scan_pass<W_, D_, false>(xb, g0, ab, act);
        __builtin_amdgcn_s_waitcnt(0);
        scan_pass<W_, D_, true>(xb, g1, ab, act);
    } else {
        const int L = (blockIdx.x - 512) * 4 + wid;  // 0..4095
        const int c = L >> 7, w = L & 127;
        const int base = (c * HW_ + w) * D_ + dl;
        const unsigned short* xb = xtb + base;
        unsigned short* ab = agg2 + base;
        const unsigned short* g2 = uni_ptr(gq + (unsigned)((2 * C_ + c) * HW_ + w * H_) * 8);
        const unsigned short* g3 = uni_ptr(gq + (unsigned)((3 * C_ + c) * HW_ + w * H_) * 8);
        scan_pass<H_, W_ * D_, false>(xb, g2, ab, act);
        __builtin_amdgcn_s_waitcnt(0);
        scan_pass<H_, W_ * D_, true>(xb, g3, ab, act);
    }
}

// blocks [0,1024): max(agg1,agg2) -> BN1 -> ReLU -> y2p[h+1][d+1][w+1][c] bf16
// blocks [1024,1584): zero the pad cells of y2p (h slabs 0/65, d rows 0/49, w cols 0/129)
__global__ __launch_bounds__(256) void k_prep(const unsigned short* __restrict__ agg1,
                                              const unsigned short* __restrict__ agg2,
                                              const float* __restrict__ bn1s,
                                              const float* __restrict__ bn1b,
                                              unsigned short* __restrict__ y2p) {
    const int t = threadIdx.x;
    if (blockIdx.x >= 1024) {
        int i = (blockIdx.x - 1024) * 256 + t;
        if (i < 143136) {
            unsigned u4i;
            if (i < 52000) {
                int slab = i / 26000, off = i % 26000;
                u4i = slab * 65 * 26000 + off;
            } else if (i < 118560) {
                int j = i - 52000;
                int h = j / 1040 + 1, r = j % 1040;
                int d = (r < 520) ? 0 : 49, off = (r < 520) ? r : r - 520;
                u4i = h * 26000 + d * 520 + off;
            } else {
                int j = i - 118560;
                int h = j / 384 + 1, r = j % 384;
                int d = (r >> 3) + 1, r2 = r & 7;
                int w = (r2 >> 2) ? 129 : 0;
                u4i = h * 26000 + d * 520 + w * 4 + (r2 & 3);
            }
            ((uint4*)y2p)[u4i] = uint4{0u, 0u, 0u, 0u};
        }
        return;
    }
    __shared__ float L[48 * 33];
    __shared__ float s_inv[32], s_b[32];
    if (t < 32) {
        s_inv[t] = bn1s[t] * rsqrtf(1.f + 1e-5f);
        s_b[t] = bn1b[t];
    }
    __syncthreads();
    const int h = blockIdx.x >> 4;
    const int w0 = (blockIdx.x & 15) * 8;
    for (int wi = 0; wi < 8; ++wi) {
        int w = w0 + wi;
#pragma unroll
        for (int i = 0; i < 6; ++i) {
            int idx = i * 256 + t;  // 0..1535
            int c = idx / 48, d = idx - c * 48;
            int off = ((c * H_ + h) * W_ + w) * D_ + d;
            float v = fmaxf(bf2f(agg1[off]), bf2f(agg2[off]));
            L[d * 33 + c] = fmaxf(v * s_inv[c] + s_b[c], 0.f);
        }
        __syncthreads();
        unsigned short* yb = y2p + (((h + 1) * 50) * 130 + (w + 1)) * 32;
#pragma unroll
        for (int i = 0; i < 6; ++i) {
            int idx = i * 256 + t;
            int c = idx & 31, d = idx >> 5;
            yb[(d + 1) * (130 * 32) + c] = f2bf(L[d * 33 + c]);
        }
        __syncthreads();
    }
}

// Conv via MFMA, LDS-staged. Block: 1h x 16w x 12d out; stage 3h x 14d x 18w x 32c.
// LDS layout [seg=kh*14+dz][w18][cpad40]; c-pad 40 -> only 2-way (free) bank aliasing.
__global__ __launch_bounds__(256) void k_conv(const unsigned short* __restrict__ y2p,
                                              const unsigned short* __restrict__ wt,
                                              const float* __restrict__ x,
                                              const float* __restrict__ bn2s,
                                              const float* __restrict__ bn2b,
                                              float* __restrict__ out) {
    __shared__ __align__(16) unsigned short ls[42 * 18 * 40];  // 60480 B
    const int t = threadIdx.x;
    const int h = blockIdx.x >> 5;
    const int ow = ((blockIdx.x >> 2) & 7) * 16;
    const int od = (blockIdx.x & 3) * 12;
    const uint4* ysrc = (const uint4*)y2p;
    for (int i = t; i < 3024; i += 256) {
        int seg = i / 72, off = i - seg * 72;
        int kh = seg / 14, dz = seg - kh * 14;
        uint4 v = ysrc[(unsigned)((h + kh) * 50 + od + dz) * 520 + ow * 4 + off];
        int w = off >> 2, cq = off & 3;
        *(uint4*)(ls + seg * 720 + w * 40 + cq * 8) = v;
    }
    __syncthreads();
    const int lane = t & 63, wid = t >> 6;
    const int n = lane & 15, kg = lane >> 4;
    const int dd0 = wid * 3;
    f32x4 acc[3][2] = {};
#pragma unroll
    for (int kh = 0; kh < 3; ++kh)
#pragma unroll
        for (int kd = 0; kd < 3; ++kd)
#pragma unroll
            for (int kw = 0; kw < 3; ++kw) {
                int tap = (kd * 3 + kh) * 3 + kw;
                short8 A0 = *(const short8*)(wt + (tap * 32 + n) * 32 + kg * 8);
                short8 A1 = *(const short8*)(wt + (tap * 32 + 16 + n) * 32 + kg * 8);
                const unsigned short* bp =
                    ls + (kh * 14 + dd0 + kd) * 720 + (n + kw) * 40 + kg * 8;
#pragma unroll
                for (int dd = 0; dd < 3; ++dd) {
                    short8 b = *(const short8*)(bp + dd * 720);
                    acc[dd][0] = __builtin_amdgcn_mfma_f32_16x16x32_bf16(A0, b, acc[dd][0], 0, 0, 0);
                    acc[dd][1] = __builtin_amdgcn_mfma_f32_16x16x32_bf16(A1, b, acc[dd][1], 0, 0, 0);
                }
            }
    const float rs = rsqrtf(1.f + 1e-5f);
#pragma unroll
    for (int ct = 0; ct < 2; ++ct)
#pragma unroll
        for (int r = 0; r < 4; ++r) {
            int co = ct * 16 + kg * 4 + r;
            float sc = bn2s[co] * rs, bi = bn2b[co];
#pragma unroll
            for (int dd = 0; dd < 3; ++dd) {
                int d = od + dd0 + dd;
                int addr = ((co * D_ + d) * H_ + h) * W_ + ow + n;
                float val = acc[dd][ct][r] * sc + bi;
                out[addr] = fmaxf(val + x[addr], 0.f);
            }
        }
}

extern "C" void kernel_launch(void* const* d_in, const int* in_sizes, int n_in,
                              void* d_out, int out_size, void* d_ws, size_t ws_size,
                              hipStream_t stream) {
    const float* x = (const float*)d_in[0];
    const float* g = (const float*)d_in[1];
    const float* wr = (const float*)d_in[2];
    const float* bn1s = (const float*)d_in[3];
    const float* bn1b = (const float*)d_in[4];
    const float* bn2s = (const float*)d_in[5];
    const float* bn2b = (const float*)d_in[6];
    float* out = (float*)d_out;
    char* ws = (char*)d_ws;

    unsigned short* xtb = (unsigned short*)ws;               // 25,165,824 B (dead after scans)
    unsigned short* y2p = (unsigned short*)ws;               // 27,456,000 B (aliases xtb)
    unsigned short* agg1 = (unsigned short*)(ws + 33554432); // 25,165,824 B
    unsigned short* agg2 = (unsigned short*)(ws + 58720256); // 25,165,824 B
    unsigned short* gq = (unsigned short*)(ws + 83886080);   // 16,777,216 B
    unsigned short* wt = (unsigned short*)(ws + 100663296);  // 55,296 B -> total 100,718,592

    k_front<<<4460, 256, 0, stream>>>(x, g, wr, xtb, gq, wt);
    k_scan<<<1536, 256, 0, stream>>>(xtb, gq, agg1, agg2);
    k_prep<<<1584, 256, 0, stream>>>(agg1, agg2, bn1s, bn1b, y2p);
    k_conv<<<2048, 256, 0, stream>>>(y2p, wt, x, bn2s, bn2b, out);
}

// Round 5
// 299.034 us; speedup vs baseline: 2.1024x; 1.0452x over previous
//
#include <hip/hip_runtime.h>

#define C_ 32
#define D_ 48
#define H_ 64
#define W_ 128
#define HW_ 8192

using short8 = __attribute__((ext_vector_type(8))) short;
using half8  = __attribute__((ext_vector_type(8))) _Float16;
using f32x4  = __attribute__((ext_vector_type(4))) float;

__device__ __forceinline__ const unsigned short* uni_ptr(const unsigned short* p) {
    unsigned long long v = (unsigned long long)p;
    unsigned lo = __builtin_amdgcn_readfirstlane((unsigned)v);
    unsigned hi = __builtin_amdgcn_readfirstlane((unsigned)(v >> 32));
    return (const unsigned short*)(((unsigned long long)hi << 32) | lo);
}

// lane n <- lane n-1 (0 fill): wf_shr1
__device__ __forceinline__ float dpp_shr1z(float v) {
    int r = __builtin_amdgcn_update_dpp(0, __builtin_bit_cast(int, v), 0x138, 0xf, 0xf, true);
    return __builtin_bit_cast(float, r);
}
// lane n <- lane n+1 (0 fill): wf_shl1. With exec=48 lanes, lane47 pulls 0.
__device__ __forceinline__ float dpp_shl1z(float v) {
    int r = __builtin_amdgcn_update_dpp(0, __builtin_bit_cast(int, v), 0x130, 0xf, 0xf, true);
    return __builtin_bit_cast(float, r);
}
// max over lanes 0..47, exec must be 48 lanes; result broadcast via lane 47.
__device__ __forceinline__ float wave_max48(float v) {
#define RMAX(ctrl)                                                                              \
    {                                                                                           \
        int t_ = __builtin_amdgcn_update_dpp(__builtin_bit_cast(int, v),                        \
                                             __builtin_bit_cast(int, v), ctrl, 0xf, 0xf, false);\
        v = fmaxf(v, __builtin_bit_cast(float, t_));                                            \
    }
    RMAX(0x111) RMAX(0x112) RMAX(0x114) RMAX(0x118) RMAX(0x142) RMAX(0x143)
#undef RMAX
    int m = __builtin_amdgcn_readlane(__builtin_bit_cast(int, v), 47);
    return __builtin_bit_cast(float, m);
}

__device__ __forceinline__ uint4 pack5(float c0, float c1, float c2, float c3, float c4) {
    float s = fabsf(c0) + fabsf(c1) + fabsf(c2) + fabsf(c3) + fabsf(c4);
    float rn = __builtin_amdgcn_rcpf(fmaxf(s, 1e-12f));
    unsigned h0 = __builtin_bit_cast(unsigned short, (_Float16)(c0 * rn));
    unsigned h1 = __builtin_bit_cast(unsigned short, (_Float16)(c1 * rn));
    unsigned h2 = __builtin_bit_cast(unsigned short, (_Float16)(c2 * rn));
    unsigned h3 = __builtin_bit_cast(unsigned short, (_Float16)(c3 * rn));
    unsigned h4 = __builtin_bit_cast(unsigned short, (_Float16)(c4 * rn));
    return uint4{h0 | (h1 << 16), h2 | (h3 << 16), h4, 0u};
}

// Fused front end:
//  blocks [0,2048):     x[c][d][h][w] fp32 -> xtb[c][h][w][d] f16
//  blocks [2048,4096):  gprep dirs 0,1 (coalesced): gq entry = 5 fp16 L1-normed weights
//  blocks [4096,4352):  gprep dirs 2,3 via LDS transpose, entries in [c][w*64+h] order
//  blocks [4352,4460):  w_refine[co][ci][tap] -> wt[tap][co][ci] f16
__global__ __launch_bounds__(256) void k_front(const float* __restrict__ x,
                                               const float* __restrict__ g,
                                               const float* __restrict__ wr,
                                               _Float16* __restrict__ xtb,
                                               unsigned short* __restrict__ gq,
                                               _Float16* __restrict__ wt) {
    __shared__ float sbuf[10560];
    const int t = threadIdx.x;
    const int bid = blockIdx.x;
    if (bid < 2048) {
        const int c = bid >> 6, h = bid & 63;
        const float* xb = x + c * (D_ * HW_) + h * W_;
#pragma unroll
        for (int i = 0; i < 24; ++i) {
            int idx = i * 256 + t;
            int d = idx >> 7, w = idx & 127;
            sbuf[d * 129 + w] = xb[d * HW_ + w];
        }
        __syncthreads();
        _Float16* xo = xtb + ((c * H_ + h) * W_) * D_;
#pragma unroll
        for (int i = 0; i < 32; ++i) {
            int idx = i * 256 + t;
            int w = idx >> 6, dl = idx & 63;
            if (dl < 48) xo[w * D_ + dl] = (_Float16)sbuf[dl * 129 + w];
        }
    } else if (bid < 4096) {
        int e = (bid - 2048) * 256 + t;  // 0..524287, dirs 0,1
        int dir = e >> 18;
        int c = (e >> 13) & 31;
        int pos = e & 8191;
        const float* gp = g + ((dir * C_ + c) * 5) * HW_ + pos;
        ((uint4*)gq)[e] = pack5(gp[0], gp[HW_], gp[2 * HW_], gp[3 * HW_], gp[4 * HW_]);
    } else if (bid < 4352) {
        int b = bid - 4096;
        int d2 = b >> 7, c = (b >> 2) & 31, w0 = (b & 3) * 32;
        const float* gp = g + (((d2 + 2) * C_ + c) * 5) * HW_;
#pragma unroll
        for (int k = 0; k < 40; ++k) {
            int j = k * 256 + t;  // 10240 = 5 x 64h x 32w
            int i = j >> 11, r = j & 2047;
            int h = r >> 5, wl = r & 31;
            sbuf[i * 2112 + h * 33 + wl] = gp[i * HW_ + h * W_ + w0 + wl];
        }
        __syncthreads();
        uint4* gqo = (uint4*)gq + ((d2 + 2) * C_ + c) * HW_;
#pragma unroll
        for (int k = 0; k < 8; ++k) {
            int j = k * 256 + t;  // 2048 = 32w x 64h
            int wl = j >> 6, h = j & 63;
            int s = h * 33 + wl;
            gqo[(w0 + wl) * 64 + h] = pack5(sbuf[s], sbuf[2112 + s], sbuf[4224 + s],
                                            sbuf[6336 + s], sbuf[8448 + s]);
        }
    } else {
        int idx = (bid - 4352) * 256 + t;  // 27648
        int ci = idx & 31, co = (idx >> 5) & 31, tap = idx >> 10;
        wt[(tap * 32 + co) * 32 + ci] = (_Float16)wr[(co * 32 + ci) * 27 + tap];
    }
}

// One directional pass. Caller guarantees exec = lanes 0..47 (lane = d).
// xb/ab per-lane element bases; gqb wave-uniform line base (ushorts).
template <int T, int SS, bool REV>
__device__ __forceinline__ void scan_pass(const _Float16* __restrict__ xb,
                                          const unsigned short* __restrict__ gqb,
                                          _Float16* __restrict__ ab) {
    constexpr int PF = 8;
    _Float16 xs[PF], as[PF];
    half8 gs[PF];
    float prev;
    {
        constexpr int q0 = REV ? (T - 1) : 0;
        prev = (float)xb[q0 * SS];
        float o = prev;
        if (REV) o = fmaxf(o, (float)ab[q0 * SS]);
        ab[q0 * SS] = (_Float16)o;
    }
#pragma unroll
    for (int i = 0; i < PF; ++i) {
        int q = REV ? (T - 2 - i) : (1 + i);
        xs[i] = xb[q * SS];
        gs[i] = *(const half8*)(gqb + q * 8);
        if (REV) as[i] = ab[q * SS];
    }
    auto step = [&](int pc, int slot) {
        _Float16 xv = xs[slot];
        half8 gh = gs[slot];
        float av = REV ? (float)as[slot] : 0.f;
        int pn = pc + PF;
        if (pn < T) {
            int qn = REV ? (T - 1 - pn) : pn;
            xs[slot] = xb[qn * SS];
            gs[slot] = *(const half8*)(gqb + qn * 8);
            if (REV) as[slot] = ab[qn * SS];
        }
        float mx = wave_max48(prev);
        float dm = dpp_shr1z(prev);
        float dp = dpp_shl1z(prev);
        float a = fmaf((float)gh[0], (float)xv, 0.f);
        a = fmaf((float)gh[1], prev, a);
        a = fmaf((float)gh[2], dm, a);
        a = fmaf((float)gh[3], dp, a);
        a = fmaf((float)gh[4], mx, a);
        float o = REV ? fmaxf(a, av) : a;
        int qq = REV ? (T - 1 - pc) : pc;
        ab[qq * SS] = (_Float16)o;
        prev = a;
    };
    int p = 1;
#pragma unroll 1
    for (; p + PF <= T; p += PF) {
#pragma unroll
        for (int i = 0; i < PF; ++i) step(p + i, i);
    }
#pragma unroll
    for (int i = 0; i < PF; ++i)
        if (p + i < T) step(p + i, i);
}

// blocks [0,512): W axis lines; [512,1536): H axis lines. fwd then rev (max-combine).
__global__ __launch_bounds__(256) void k_scan(const _Float16* __restrict__ xtb,
                                              const unsigned short* __restrict__ gq,
                                              _Float16* __restrict__ agg1,
                                              _Float16* __restrict__ agg2) {
    const int lane = threadIdx.x & 63;
    const int wid = threadIdx.x >> 6;
    if (lane >= 48) return;  // exec = 48 lanes for the whole body
    if (blockIdx.x < 512) {
        const int L = blockIdx.x * 4 + wid;  // 0..2047
        const int c = L >> 6, h = L & 63;
        const int base = ((c * H_ + h) * W_) * D_ + lane;
        const _Float16* xb = xtb + base;
        _Float16* ab = agg1 + base;
        const unsigned short* g0 = uni_ptr(gq + (unsigned)((0 * C_ + c) * HW_ + h * W_) * 8);
        const unsigned short* g1 = uni_ptr(gq + (unsigned)((1 * C_ + c) * HW_ + h * W_) * 8);
        scan_pass<W_, D_, false>(xb, g0, ab);
        __builtin_amdgcn_s_waitcnt(0);
        scan_pass<W_, D_, true>(xb, g1, ab);
    } else {
        const int L = (blockIdx.x - 512) * 4 + wid;  // 0..4095
        const int c = L >> 7, w = L & 127;
        const int base = (c * HW_ + w) * D_ + lane;
        const _Float16* xb = xtb + base;
        _Float16* ab = agg2 + base;
        const unsigned short* g2 = uni_ptr(gq + (unsigned)((2 * C_ + c) * HW_ + w * H_) * 8);
        const unsigned short* g3 = uni_ptr(gq + (unsigned)((3 * C_ + c) * HW_ + w * H_) * 8);
        scan_pass<H_, W_ * D_, false>(xb, g2, ab);
        __builtin_amdgcn_s_waitcnt(0);
        scan_pass<H_, W_ * D_, true>(xb, g3, ab);
    }
}

// blocks [0,1024): max(agg1,agg2) -> BN1 -> ReLU -> y2p[h+1][d+1][w+1][c] f16
// blocks [1024,1584): zero the pad cells of y2p (h slabs 0/65, d rows 0/49, w cols 0/129)
__global__ __launch_bounds__(256) void k_prep(const _Float16* __restrict__ agg1,
                                              const _Float16* __restrict__ agg2,
                                              const float* __restrict__ bn1s,
                                              const float* __restrict__ bn1b,
                                              _Float16* __restrict__ y2p) {
    const int t = threadIdx.x;
    if (blockIdx.x >= 1024) {
        int i = (blockIdx.x - 1024) * 256 + t;
        if (i < 143136) {
            unsigned u4i;
            if (i < 52000) {
                int slab = i / 26000, off = i % 26000;
                u4i = slab * 65 * 26000 + off;
            } else if (i < 118560) {
                int j = i - 52000;
                int h = j / 1040 + 1, r = j % 1040;
                int d = (r < 520) ? 0 : 49, off = (r < 520) ? r : r - 520;
                u4i = h * 26000 + d * 520 + off;
            } else {
                int j = i - 118560;
                int h = j / 384 + 1, r = j % 384;
                int d = (r >> 3) + 1, r2 = r & 7;
                int w = (r2 >> 2) ? 129 : 0;
                u4i = h * 26000 + d * 520 + w * 4 + (r2 & 3);
            }
            ((uint4*)y2p)[u4i] = uint4{0u, 0u, 0u, 0u};
        }
        return;
    }
    __shared__ float L[48 * 33];
    __shared__ float s_inv[32], s_b[32];
    if (t < 32) {
        s_inv[t] = bn1s[t] * rsqrtf(1.f + 1e-5f);
        s_b[t] = bn1b[t];
    }
    __syncthreads();
    const int h = blockIdx.x >> 4;
    const int w0 = (blockIdx.x & 15) * 8;
    for (int wi = 0; wi < 8; ++wi) {
        int w = w0 + wi;
#pragma unroll
        for (int i = 0; i < 6; ++i) {
            int idx = i * 256 + t;  // 0..1535
            int c = idx / 48, d = idx - c * 48;
            int off = ((c * H_ + h) * W_ + w) * D_ + d;
            float v = fmaxf((float)agg1[off], (float)agg2[off]);
            L[d * 33 + c] = fmaxf(v * s_inv[c] + s_b[c], 0.f);
        }
        __syncthreads();
        _Float16* yb = y2p + (((h + 1) * 50) * 130 + (w + 1)) * 32;
#pragma unroll
        for (int i = 0; i < 6; ++i) {
            int idx = i * 256 + t;
            int c = idx & 31, d = idx >> 5;
            yb[(d + 1) * (130 * 32) + c] = (_Float16)L[d * 33 + c];
        }
        __syncthreads();
    }
}

// Conv via MFMA f16, LDS-staged. Block: 1h x 16w x 12d out; stage 3h x 14d x 18w x 32c.
// LDS layout [seg=kh*14+dz][w18][cpad40]; c-pad 40 -> only 2-way (free) bank aliasing.
__global__ __launch_bounds__(256) void k_conv(const _Float16* __restrict__ y2p,
                                              const _Float16* __restrict__ wt,
                                              const float* __restrict__ x,
                                              const float* __restrict__ bn2s,
                                              const float* __restrict__ bn2b,
                                              float* __restrict__ out) {
    __shared__ __align__(16) unsigned short ls[42 * 18 * 40];  // 60480 B
    const int t = threadIdx.x;
    const int h = blockIdx.x >> 5;
    const int ow = ((blockIdx.x >> 2) & 7) * 16;
    const int od = (blockIdx.x & 3) * 12;
    const uint4* ysrc = (const uint4*)y2p;
    for (int i = t; i < 3024; i += 256) {
        int seg = i / 72, off = i - seg * 72;
        int kh = seg / 14, dz = seg - kh * 14;
        uint4 v = ysrc[(unsigned)((h + kh) * 50 + od + dz) * 520 + ow * 4 + off];
        int w = off >> 2, cq = off & 3;
        *(uint4*)(ls + seg * 720 + w * 40 + cq * 8) = v;
    }
    __syncthreads();
    const int lane = t & 63, wid = t >> 6;
    const int n = lane & 15, kg = lane >> 4;
    const int dd0 = wid * 3;
    f32x4 acc[3][2] = {};
#pragma unroll
    for (int kh = 0; kh < 3; ++kh)
#pragma unroll
        for (int kd = 0; kd < 3; ++kd)
#pragma unroll
            for (int kw = 0; kw < 3; ++kw) {
                int tap = (kd * 3 + kh) * 3 + kw;
                half8 A0 = *(const half8*)(wt + (tap * 32 + n) * 32 + kg * 8);
                half8 A1 = *(const half8*)(wt + (tap * 32 + 16 + n) * 32 + kg * 8);
                const unsigned short* bp =
                    ls + (kh * 14 + dd0 + kd) * 720 + (n + kw) * 40 + kg * 8;
#pragma unroll
                for (int dd = 0; dd < 3; ++dd) {
                    half8 b = __builtin_bit_cast(half8, *(const short8*)(bp + dd * 720));
                    acc[dd][0] = __builtin_amdgcn_mfma_f32_16x16x32_f16(A0, b, acc[dd][0], 0, 0, 0);
                    acc[dd][1] = __builtin_amdgcn_mfma_f32_16x16x32_f16(A1, b, acc[dd][1], 0, 0, 0);
                }
            }
    const float rs = rsqrtf(1.f + 1e-5f);
#pragma unroll
    for (int ct = 0; ct < 2; ++ct)
#pragma unroll
        for (int r = 0; r < 4; ++r) {
            int co = ct * 16 + kg * 4 + r;
            float sc = bn2s[co] * rs, bi = bn2b[co];
#pragma unroll
            for (int dd = 0; dd < 3; ++dd) {
                int d = od + dd0 + dd;
                int addr = ((co * D_ + d) * H_ + h) * W_ + ow + n;
                float val = acc[dd][ct][r] * sc + bi;
                out[addr] = fmaxf(val + x[addr], 0.f);
            }
        }
}

extern "C" void kernel_launch(void* const* d_in, const int* in_sizes, int n_in,
                              void* d_out, int out_size, void* d_ws, size_t ws_size,
                              hipStream_t stream) {
    const float* x = (const float*)d_in[0];
    const float* g = (const float*)d_in[1];
    const float* wr = (const float*)d_in[2];
    const float* bn1s = (const float*)d_in[3];
    const float* bn1b = (const float*)d_in[4];
    const float* bn2s = (const float*)d_in[5];
    const float* bn2b = (const float*)d_in[6];
    float* out = (float*)d_out;
    char* ws = (char*)d_ws;

    _Float16* xtb = (_Float16*)ws;                       // 25,165,824 B (dead after scans)
    _Float16* y2p = (_Float16*)ws;                       // 27,456,000 B (aliases xtb)
    _Float16* agg1 = (_Float16*)(ws + 33554432);         // 25,165,824 B
    _Float16* agg2 = (_Float16*)(ws + 58720256);         // 25,165,824 B
    unsigned short* gq = (unsigned short*)(ws + 83886080);  // 16,777,216 B
    _Float16* wt = (_Float16*)(ws + 100663296);          // 55,296 B -> total 100,718,592

    k_front<<<4460, 256, 0, stream>>>(x, g, wr, xtb, gq, wt);
    k_scan<<<1536, 256, 0, stream>>>(xtb, gq, agg1, agg2);
    k_prep<<<1584, 256, 0, stream>>>(agg1, agg2, bn1s, bn1b, y2p);
    k_conv<<<2048, 256, 0, stream>>>(y2p, wt, x, bn2s, bn2b, out);
}

// Round 6
// 276.008 us; speedup vs baseline: 2.2778x; 1.0834x over previous
//
#include <hip/hip_runtime.h>

#define C_ 32
#define D_ 48
#define H_ 64
#define W_ 128
#define HW_ 8192

using short8 = __attribute__((ext_vector_type(8))) short;
using half8  = __attribute__((ext_vector_type(8))) _Float16;
using half4  = __attribute__((ext_vector_type(4))) _Float16;
using half2v = __attribute__((ext_vector_type(2))) _Float16;
using f32x4  = __attribute__((ext_vector_type(4))) float;

__device__ __forceinline__ const unsigned short* uni_ptr(const unsigned short* p) {
    unsigned long long v = (unsigned long long)p;
    unsigned lo = __builtin_amdgcn_readfirstlane((unsigned)v);
    unsigned hi = __builtin_amdgcn_readfirstlane((unsigned)(v >> 32));
    return (const unsigned short*)(((unsigned long long)hi << 32) | lo);
}

// lane n <- lane n-1 (0 fill): wf_shr1
__device__ __forceinline__ float dpp_shr1z(float v) {
    int r = __builtin_amdgcn_update_dpp(0, __builtin_bit_cast(int, v), 0x138, 0xf, 0xf, true);
    return __builtin_bit_cast(float, r);
}
// lane n <- lane n+1 (0 fill): wf_shl1. With exec=48 lanes, lane47 pulls 0.
__device__ __forceinline__ float dpp_shl1z(float v) {
    int r = __builtin_amdgcn_update_dpp(0, __builtin_bit_cast(int, v), 0x130, 0xf, 0xf, true);
    return __builtin_bit_cast(float, r);
}
// max over lanes 0..47, exec must be 48 lanes; result broadcast via lane 47.
__device__ __forceinline__ float wave_max48(float v) {
#define RMAX(ctrl)                                                                              \
    {                                                                                           \
        int t_ = __builtin_amdgcn_update_dpp(__builtin_bit_cast(int, v),                        \
                                             __builtin_bit_cast(int, v), ctrl, 0xf, 0xf, false);\
        v = fmaxf(v, __builtin_bit_cast(float, t_));                                            \
    }
    RMAX(0x111) RMAX(0x112) RMAX(0x114) RMAX(0x118) RMAX(0x142) RMAX(0x143)
#undef RMAX
    int m = __builtin_amdgcn_readlane(__builtin_bit_cast(int, v), 47);
    return __builtin_bit_cast(float, m);
}

__device__ __forceinline__ uint4 pack5(float c0, float c1, float c2, float c3, float c4) {
    float s = fabsf(c0) + fabsf(c1) + fabsf(c2) + fabsf(c3) + fabsf(c4);
    float rn = __builtin_amdgcn_rcpf(fmaxf(s, 1e-12f));
    unsigned h0 = __builtin_bit_cast(unsigned short, (_Float16)(c0 * rn));
    unsigned h1 = __builtin_bit_cast(unsigned short, (_Float16)(c1 * rn));
    unsigned h2 = __builtin_bit_cast(unsigned short, (_Float16)(c2 * rn));
    unsigned h3 = __builtin_bit_cast(unsigned short, (_Float16)(c3 * rn));
    unsigned h4 = __builtin_bit_cast(unsigned short, (_Float16)(c4 * rn));
    return uint4{h0 | (h1 << 16), h2 | (h3 << 16), h4, 0u};
}

// Fused front end:
//  blocks [0,2048):     x[c][d][h][w] fp32 -> xtb[c][h][w][d] f16 (vectorized)
//  blocks [2048,4096):  gprep dirs 0,1 (coalesced): gq entry = 5 fp16 L1-normed weights
//  blocks [4096,4352):  gprep dirs 2,3 via LDS transpose, entries in [c][w*64+h] order
//  blocks [4352,4460):  w_refine[co][ci][tap] -> wt[tap][co][ci] f16
__global__ __launch_bounds__(256) void k_front(const float* __restrict__ x,
                                               const float* __restrict__ g,
                                               const float* __restrict__ wr,
                                               _Float16* __restrict__ xtb,
                                               unsigned short* __restrict__ gq,
                                               _Float16* __restrict__ wt) {
    __shared__ float sbuf[10560];
    const int t = threadIdx.x;
    const int bid = blockIdx.x;
    if (bid < 2048) {
        const int c = bid >> 6, h = bid & 63;
        const float4* xb4 = (const float4*)(x + c * (D_ * HW_) + h * W_);
#pragma unroll
        for (int i = 0; i < 6; ++i) {
            int idx = i * 256 + t;  // 1536 float4 = 48d x 32wq
            int d = idx >> 5, wq = idx & 31;
            float4 v = xb4[d * 2048 + wq];
            sbuf[d * 129 + wq * 4 + 0] = v.x;
            sbuf[d * 129 + wq * 4 + 1] = v.y;
            sbuf[d * 129 + wq * 4 + 2] = v.z;
            sbuf[d * 129 + wq * 4 + 3] = v.w;
        }
        __syncthreads();
        half4* xo4 = (half4*)(xtb + ((c * H_ + h) * W_) * D_);
#pragma unroll
        for (int i = 0; i < 6; ++i) {
            int idx = i * 256 + t;  // 1536 half4 = 128w x 12dq
            int w = idx / 12, dq = idx - w * 12;
            half4 hv;
#pragma unroll
            for (int k = 0; k < 4; ++k) hv[k] = (_Float16)sbuf[(dq * 4 + k) * 129 + w];
            xo4[w * 12 + dq] = hv;
        }
    } else if (bid < 4096) {
        int e = (bid - 2048) * 256 + t;  // 0..524287, dirs 0,1
        int dir = e >> 18;
        int c = (e >> 13) & 31;
        int pos = e & 8191;
        const float* gp = g + ((dir * C_ + c) * 5) * HW_ + pos;
        ((uint4*)gq)[e] = pack5(gp[0], gp[HW_], gp[2 * HW_], gp[3 * HW_], gp[4 * HW_]);
    } else if (bid < 4352) {
        int b = bid - 4096;
        int d2 = b >> 7, c = (b >> 2) & 31, w0 = (b & 3) * 32;
        const float* gp = g + (((d2 + 2) * C_ + c) * 5) * HW_;
#pragma unroll
        for (int k = 0; k < 40; ++k) {
            int j = k * 256 + t;  // 10240 = 5 x 64h x 32w
            int i = j >> 11, r = j & 2047;
            int h = r >> 5, wl = r & 31;
            sbuf[i * 2112 + h * 33 + wl] = gp[i * HW_ + h * W_ + w0 + wl];
        }
        __syncthreads();
        uint4* gqo = (uint4*)gq + ((d2 + 2) * C_ + c) * HW_;
#pragma unroll
        for (int k = 0; k < 8; ++k) {
            int j = k * 256 + t;  // 2048 = 32w x 64h
            int wl = j >> 6, h = j & 63;
            int s = h * 33 + wl;
            gqo[(w0 + wl) * 64 + h] = pack5(sbuf[s], sbuf[2112 + s], sbuf[4224 + s],
                                            sbuf[6336 + s], sbuf[8448 + s]);
        }
    } else {
        int idx = (bid - 4352) * 256 + t;  // 27648
        int ci = idx & 31, co = (idx >> 5) & 31, tap = idx >> 10;
        wt[(tap * 32 + co) * 32 + ci] = (_Float16)wr[(co * 32 + ci) * 27 + tap];
    }
}

// One directional pass. Caller guarantees exec = lanes 0..47 (lane = d).
// xb/ab per-lane element bases; gqb wave-uniform line base (ushorts).
template <int T, int SS, bool REV>
__device__ __forceinline__ void scan_pass(const _Float16* __restrict__ xb,
                                          const unsigned short* __restrict__ gqb,
                                          _Float16* __restrict__ ab) {
    constexpr int PF = 8;
    _Float16 xs[PF], as[PF];
    half8 gs[PF];
    float prev;
    {
        constexpr int q0 = REV ? (T - 1) : 0;
        prev = (float)xb[q0 * SS];
        float o = prev;
        if (REV) o = fmaxf(o, (float)ab[q0 * SS]);
        ab[q0 * SS] = (_Float16)o;
    }
#pragma unroll
    for (int i = 0; i < PF; ++i) {
        int q = REV ? (T - 2 - i) : (1 + i);
        xs[i] = xb[q * SS];
        gs[i] = *(const half8*)(gqb + q * 8);
        if (REV) as[i] = ab[q * SS];
    }
    auto step = [&](int pc, int slot) {
        _Float16 xv = xs[slot];
        half8 gh = gs[slot];
        float av = REV ? (float)as[slot] : 0.f;
        int pn = pc + PF;
        if (pn < T) {
            int qn = REV ? (T - 1 - pn) : pn;
            xs[slot] = xb[qn * SS];
            gs[slot] = *(const half8*)(gqb + qn * 8);
            if (REV) as[slot] = ab[qn * SS];
        }
        float mx = wave_max48(prev);
        float dm = dpp_shr1z(prev);
        float dp = dpp_shl1z(prev);
        float a = fmaf((float)gh[0], (float)xv, 0.f);
        a = fmaf((float)gh[1], prev, a);
        a = fmaf((float)gh[2], dm, a);
        a = fmaf((float)gh[3], dp, a);
        a = fmaf((float)gh[4], mx, a);
        float o = REV ? fmaxf(a, av) : a;
        int qq = REV ? (T - 1 - pc) : pc;
        ab[qq * SS] = (_Float16)o;
        prev = a;
    };
    int p = 1;
#pragma unroll 1
    for (; p + PF <= T; p += PF) {
#pragma unroll
        for (int i = 0; i < PF; ++i) step(p + i, i);
    }
#pragma unroll
    for (int i = 0; i < PF; ++i)
        if (p + i < T) step(p + i, i);
}

// blocks [0,512): W axis lines; [512,1536): H axis lines. fwd then rev (max-combine).
__global__ __launch_bounds__(256) void k_scan(const _Float16* __restrict__ xtb,
                                              const unsigned short* __restrict__ gq,
                                              _Float16* __restrict__ agg1,
                                              _Float16* __restrict__ agg2) {
    const int lane = threadIdx.x & 63;
    const int wid = threadIdx.x >> 6;
    if (lane >= 48) return;  // exec = 48 lanes for the whole body
    if (blockIdx.x < 512) {
        const int L = blockIdx.x * 4 + wid;  // 0..2047
        const int c = L >> 6, h = L & 63;
        const int base = ((c * H_ + h) * W_) * D_ + lane;
        const _Float16* xb = xtb + base;
        _Float16* ab = agg1 + base;
        const unsigned short* g0 = uni_ptr(gq + (unsigned)((0 * C_ + c) * HW_ + h * W_) * 8);
        const unsigned short* g1 = uni_ptr(gq + (unsigned)((1 * C_ + c) * HW_ + h * W_) * 8);
        scan_pass<W_, D_, false>(xb, g0, ab);
        __builtin_amdgcn_s_waitcnt(0);
        scan_pass<W_, D_, true>(xb, g1, ab);
    } else {
        const int L = (blockIdx.x - 512) * 4 + wid;  // 0..4095
        const int c = L >> 7, w = L & 127;
        const int base = (c * HW_ + w) * D_ + lane;
        const _Float16* xb = xtb + base;
        _Float16* ab = agg2 + base;
        const unsigned short* g2 = uni_ptr(gq + (unsigned)((2 * C_ + c) * HW_ + w * H_) * 8);
        const unsigned short* g3 = uni_ptr(gq + (unsigned)((3 * C_ + c) * HW_ + w * H_) * 8);
        scan_pass<H_, W_ * D_, false>(xb, g2, ab);
        __builtin_amdgcn_s_waitcnt(0);
        scan_pass<H_, W_ * D_, true>(xb, g3, ab);
    }
}

// blocks [0,1024): max(agg1,agg2) -> BN1 -> ReLU -> y2p[h+1][d+1][w+1][c] f16
// blocks [1024,1584): zero the pad cells of y2p (h slabs 0/65, d rows 0/49, w cols 0/129)
__global__ __launch_bounds__(256) void k_prep(const _Float16* __restrict__ agg1,
                                              const _Float16* __restrict__ agg2,
                                              const float* __restrict__ bn1s,
                                              const float* __restrict__ bn1b,
                                              _Float16* __restrict__ y2p) {
    const int t = threadIdx.x;
    if (blockIdx.x >= 1024) {
        int i = (blockIdx.x - 1024) * 256 + t;
        if (i < 143136) {
            unsigned u4i;
            if (i < 52000) {
                int slab = i / 26000, off = i % 26000;
                u4i = slab * 65 * 26000 + off;
            } else if (i < 118560) {
                int j = i - 52000;
                int h = j / 1040 + 1, r = j % 1040;
                int d = (r < 520) ? 0 : 49, off = (r < 520) ? r : r - 520;
                u4i = h * 26000 + d * 520 + off;
            } else {
                int j = i - 118560;
                int h = j / 384 + 1, r = j % 384;
                int d = (r >> 3) + 1, r2 = r & 7;
                int w = (r2 >> 2) ? 129 : 0;
                u4i = h * 26000 + d * 520 + w * 4 + (r2 & 3);
            }
            ((uint4*)y2p)[u4i] = uint4{0u, 0u, 0u, 0u};
        }
        return;
    }
    __shared__ float L[48 * 33];
    __shared__ float s_inv[32], s_b[32];
    if (t < 32) {
        s_inv[t] = bn1s[t] * rsqrtf(1.f + 1e-5f);
        s_b[t] = bn1b[t];
    }
    __syncthreads();
    const int h = blockIdx.x >> 4;
    const int w0 = (blockIdx.x & 15) * 8;
    const half4* a14 = (const half4*)agg1;
    const half4* a24 = (const half4*)agg2;
    for (int wi = 0; wi < 8; ++wi) {
        int w = w0 + wi;
        for (int i = t; i < 384; i += 256) {  // 384 half4 = 32c x 12dq
            int c = i / 12, dq = i - c * 12;
            int ao = ((c * H_ + h) * W_ + w) * 12 + dq;
            half4 u1 = a14[ao];
            half4 u2 = a24[ao];
            float si = s_inv[c], sb = s_b[c];
#pragma unroll
            for (int k = 0; k < 4; ++k) {
                float v = fmaxf((float)u1[k], (float)u2[k]);
                L[(dq * 4 + k) * 33 + c] = fmaxf(v * si + sb, 0.f);
            }
        }
        __syncthreads();
        half2v* yb2 = (half2v*)y2p;
#pragma unroll
        for (int i = 0; i < 3; ++i) {
            int idx = i * 256 + t;  // 768 = 48d x 16c2
            int c2 = idx & 15, d = idx >> 4;
            half2v hv;
            hv[0] = (_Float16)L[d * 33 + c2 * 2];
            hv[1] = (_Float16)L[d * 33 + c2 * 2 + 1];
            yb2[(((h + 1) * 50 + (d + 1)) * 130 + (w + 1)) * 16 + c2] = hv;
        }
        __syncthreads();
    }
}

// Conv via MFMA f16. Linear LDS [seg=kh*14+dz][w18][c32] staged with global_load_lds.
// Block: 1h x 16w x 12d out; 3 blocks/CU (48 KB + pad). B ds_reads conflict-free.
__global__ __launch_bounds__(256, 3) void k_conv(const _Float16* __restrict__ y2p,
                                                 const _Float16* __restrict__ wt,
                                                 const float* __restrict__ x,
                                                 const float* __restrict__ bn2s,
                                                 const float* __restrict__ bn2b,
                                                 float* __restrict__ out) {
    __shared__ __align__(16) unsigned short ls[24576];  // 49152 B
    const int t = threadIdx.x;
    const int lane = t & 63, wid = t >> 6;
    const int h = blockIdx.x >> 5;
    const int ow = ((blockIdx.x >> 2) & 7) * 16;
    const int od = (blockIdx.x & 3) * 12;
    // Stage 3024 x 16 B: element i -> lds byte i*16. seg = i/72 (kh,dz), off = i%72 (w,cq).
    {
        const int j0 = wid * 12;
#pragma unroll
        for (int jj = 0; jj < 12; ++jj) {
            int j = j0 + jj;
            int i = j * 64 + lane;
            int seg = i / 72, off = i - seg * 72;
            int kh = seg / 14, dz = seg - kh * 14;
            const _Float16* gp = y2p + (unsigned)(((h + kh) * 50 + od + dz) * 520 + ow * 4 + off) * 8;
            if (i < 3024)
                __builtin_amdgcn_global_load_lds(
                    (const __attribute__((address_space(1))) void*)gp,
                    (__attribute__((address_space(3))) void*)(ls + (unsigned)j * 512), 16, 0, 0);
        }
    }
    __syncthreads();
    const int n = lane & 15, kg = lane >> 4;
    const int dd0 = wid * 3;
    f32x4 acc[3][2] = {};
#pragma unroll
    for (int kh = 0; kh < 3; ++kh)
#pragma unroll
        for (int kd = 0; kd < 3; ++kd)
#pragma unroll
            for (int kw = 0; kw < 3; ++kw) {
                int tap = (kd * 3 + kh) * 3 + kw;
                half8 A0 = *(const half8*)(wt + (tap * 32 + n) * 32 + kg * 8);
                half8 A1 = *(const half8*)(wt + (tap * 32 + 16 + n) * 32 + kg * 8);
                const unsigned short* bp =
                    ls + (kh * 14 + dd0 + kd) * 576 + (n + kw) * 32 + kg * 8;
#pragma unroll
                for (int dd = 0; dd < 3; ++dd) {
                    half8 b = __builtin_bit_cast(half8, *(const short8*)(bp + dd * 576));
                    acc[dd][0] = __builtin_amdgcn_mfma_f32_16x16x32_f16(A0, b, acc[dd][0], 0, 0, 0);
                    acc[dd][1] = __builtin_amdgcn_mfma_f32_16x16x32_f16(A1, b, acc[dd][1], 0, 0, 0);
                }
            }
    const float rs = rsqrtf(1.f + 1e-5f);
#pragma unroll
    for (int ct = 0; ct < 2; ++ct)
#pragma unroll
        for (int r = 0; r < 4; ++r) {
            int co = ct * 16 + kg * 4 + r;
            float sc = bn2s[co] * rs, bi = bn2b[co];
#pragma unroll
            for (int dd = 0; dd < 3; ++dd) {
                int d = od + dd0 + dd;
                int addr = ((co * D_ + d) * H_ + h) * W_ + ow + n;
                float val = acc[dd][ct][r] * sc + bi;
                out[addr] = fmaxf(val + x[addr], 0.f);
            }
        }
}

extern "C" void kernel_launch(void* const* d_in, const int* in_sizes, int n_in,
                              void* d_out, int out_size, void* d_ws, size_t ws_size,
                              hipStream_t stream) {
    const float* x = (const float*)d_in[0];
    const float* g = (const float*)d_in[1];
    const float* wr = (const float*)d_in[2];
    const float* bn1s = (const float*)d_in[3];
    const float* bn1b = (const float*)d_in[4];
    const float* bn2s = (const float*)d_in[5];
    const float* bn2b = (const float*)d_in[6];
    float* out = (float*)d_out;
    char* ws = (char*)d_ws;

    _Float16* xtb = (_Float16*)ws;                       // 25,165,824 B (dead after scans)
    _Float16* y2p = (_Float16*)ws;                       // 27,456,000 B (aliases xtb)
    _Float16* agg1 = (_Float16*)(ws + 33554432);         // 25,165,824 B
    _Float16* agg2 = (_Float16*)(ws + 58720256);         // 25,165,824 B
    unsigned short* gq = (unsigned short*)(ws + 83886080);  // 16,777,216 B
    _Float16* wt = (_Float16*)(ws + 100663296);          // 55,296 B -> total 100,718,592

    k_front<<<4460, 256, 0, stream>>>(x, g, wr, xtb, gq, wt);
    k_scan<<<1536, 256, 0, stream>>>(xtb, gq, agg1, agg2);
    k_prep<<<1584, 256, 0, stream>>>(agg1, agg2, bn1s, bn1b, y2p);
    k_conv<<<2048, 256, 0, stream>>>(y2p, wt, x, bn2s, bn2b, out);
}